// Round 1
// baseline (717.053 us; speedup 1.0000x reference)
//
#include <hip/hip_runtime.h>
#include <stdint.h>

typedef unsigned short u16;
typedef __bf16 bfv8 __attribute__((ext_vector_type(8)));
typedef float f32x4 __attribute__((ext_vector_type(4)));
typedef unsigned short u16x8 __attribute__((ext_vector_type(8)));

#define DI __device__ __forceinline__

DI u16 f2bf(float f) {
  union { float f; unsigned u; } c; c.f = f;
  unsigned r = c.u + 0x7FFFu + ((c.u >> 16) & 1u);
  return (u16)(r >> 16);
}
DI float bf2f(u16 b) {
  union { unsigned u; float f; } c; c.u = ((unsigned)b) << 16;
  return c.f;
}

enum { EPI_BF16 = 0, EPI_RELU2 = 1, EPI_ADDF32 = 2, EPI_QK = 3 };

// C[m,n] = sum_k A[m,k] * Bt[n,k].  128x128 tile, BK=64, 4 waves, 16x16x32 bf16 MFMA.
// Batch z = blockIdx.z decomposed as zq=z>>2, zr=z&3; base offsets = zq*Xq + zr*Xr.
// KSPLIT: for k>=ksp, A comes from A2 (no batch offset), B from B2 (batched).
// LDS XOR-swizzle: phys chunk (row,kc) holds global chunk (row, kc^(row&7)).
template <int EPI, bool KSPLIT>
__global__ __launch_bounds__(256) void gemm_core(
    const u16* __restrict__ A1, long a1q, long a1r, int lda1,
    const u16* __restrict__ A2, int lda2,
    const u16* __restrict__ B1, long b1q, long b1r, int ldb1,
    const u16* __restrict__ B2, long b2q, long b2r, int ldb2,
    int K, int ksp,
    void* __restrict__ Cv, long cq, long cr, int ldc,
    const float* __restrict__ extra, long eq, int lde,
    float scale)
{
  __shared__ __align__(16) u16 As[128 * 64];
  __shared__ __align__(16) u16 Bs[128 * 64];
  const int tid = threadIdx.x;
  const int wid = tid >> 6, lane = tid & 63;
  const long zq = blockIdx.z >> 2, zr = blockIdx.z & 3;
  const int m0 = blockIdx.y * 128, n0 = blockIdx.x * 128;
  const u16* Ab = A1 + zq * a1q + zr * a1r;
  const u16* Bb = B1 + zq * b1q + zr * b1r;
  const u16* B2b = KSPLIT ? (B2 + zq * b2q + zr * b2r) : (const u16*)nullptr;

  f32x4 acc[4][4];
#pragma unroll
  for (int i = 0; i < 4; ++i)
#pragma unroll
    for (int j = 0; j < 4; ++j)
      acc[i][j] = (f32x4){0.f, 0.f, 0.f, 0.f};

  const int wm = (wid >> 1) * 64, wn = (wid & 1) * 64;
  const int fr = lane & 15, fq = lane >> 4;

  for (int k0 = 0; k0 < K; k0 += 64) {
    __syncthreads();
    const bool first = (!KSPLIT) || (k0 < ksp);
#pragma unroll
    for (int p = 0; p < 4; ++p) {
      int idx = (p << 8) + tid;          // chunk index in [0,1024)
      int row = idx >> 3;                // tile row
      int kcs = ((idx & 7) ^ (row & 7)) << 3;  // swizzled source column (elements)
      const u16* ga;
      const u16* gb;
      if (first) {
        ga = Ab + (size_t)(m0 + row) * lda1 + k0 + kcs;
        gb = Bb + (size_t)(n0 + row) * ldb1 + k0 + kcs;
      } else {
        ga = A2 + (size_t)(m0 + row) * lda2 + (k0 - ksp) + kcs;
        gb = B2b + (size_t)(n0 + row) * ldb2 + (k0 - ksp) + kcs;
      }
      // wave-uniform LDS base: (p*256 + wid*64) chunks * 8 elems
      u16* la = &As[((p << 2) + wid) << 9];
      u16* lb = &Bs[((p << 2) + wid) << 9];
      __builtin_amdgcn_global_load_lds((const __attribute__((address_space(1))) void*)ga,
                                       (__attribute__((address_space(3))) void*)la, 16, 0, 0);
      __builtin_amdgcn_global_load_lds((const __attribute__((address_space(1))) void*)gb,
                                       (__attribute__((address_space(3))) void*)lb, 16, 0, 0);
    }
    __syncthreads();
#pragma unroll
    for (int ks = 0; ks < 2; ++ks) {
      bfv8 av[4], bv[4];
#pragma unroll
      for (int i = 0; i < 4; ++i) {
        int ra = wm + i * 16 + fr;
        int ca = (((ks << 2) + fq) ^ (ra & 7)) << 3;
        av[i] = *(const bfv8*)&As[(ra << 6) + ca];
        int rb = wn + i * 16 + fr;
        int cb = (((ks << 2) + fq) ^ (rb & 7)) << 3;
        bv[i] = *(const bfv8*)&Bs[(rb << 6) + cb];
      }
#pragma unroll
      for (int i = 0; i < 4; ++i)
#pragma unroll
        for (int j = 0; j < 4; ++j)
          acc[i][j] = __builtin_amdgcn_mfma_f32_16x16x32_bf16(av[i], bv[j], acc[i][j], 0, 0, 0);
    }
  }

  if constexpr (EPI == EPI_BF16 || EPI == EPI_RELU2) {
    u16* Cb = (u16*)Cv + zq * cq + zr * cr;
#pragma unroll
    for (int i = 0; i < 4; ++i)
#pragma unroll
      for (int j = 0; j < 4; ++j)
#pragma unroll
        for (int r = 0; r < 4; ++r) {
          int row = m0 + wm + i * 16 + (fq << 2) + r;
          int col = n0 + wn + j * 16 + fr;
          float v = acc[i][j][r];
          if constexpr (EPI == EPI_RELU2) { v = fmaxf(v, 0.f); v = v * v; }
          Cb[(size_t)row * ldc + col] = f2bf(v);
        }
  } else if constexpr (EPI == EPI_ADDF32) {
    float* Cb = (float*)Cv + zq * cq + zr * cr;
#pragma unroll
    for (int i = 0; i < 4; ++i)
#pragma unroll
      for (int j = 0; j < 4; ++j)
#pragma unroll
        for (int r = 0; r < 4; ++r) {
          int row = m0 + wm + i * 16 + (fq << 2) + r;
          int col = n0 + wn + j * 16 + fr;
          Cb[(size_t)row * ldc + col] += acc[i][j][r];
        }
  } else {  // EPI_QK
    float* Cb = (float*)Cv + zq * cq + zr * cr;
    const float* Eb = extra + (size_t)blockIdx.z * eq;
#pragma unroll
    for (int i = 0; i < 4; ++i)
#pragma unroll
      for (int j = 0; j < 4; ++j)
#pragma unroll
        for (int r = 0; r < 4; ++r) {
          int row = m0 + wm + i * 16 + (fq << 2) + r;
          int col = n0 + wn + j * 16 + fr;
          Cb[(size_t)row * ldc + col] = acc[i][j][r] * scale + Eb[(size_t)row * lde + col];
        }
  }
}

// xs[b,w,h] = sum_c x[b,c,h,w]*w8[c] + bias ; out f32 or bf16
__global__ __launch_bounds__(1024) void proj_kernel(const float* __restrict__ x,
                                                    const float* __restrict__ w8,
                                                    const float* __restrict__ bias,
                                                    void* __restrict__ out, int out_bf16)
{
  __shared__ float t[32][33];
  int b = blockIdx.z;
  int h = blockIdx.y * 32 + threadIdx.y;
  int w = blockIdx.x * 32 + threadIdx.x;
  float acc = bias[0];
#pragma unroll
  for (int c = 0; c < 8; ++c)
    acc += x[(((size_t)b * 8 + c) * 1024 + h) * 1024 + w] * w8[c];
  t[threadIdx.y][threadIdx.x] = acc;
  __syncthreads();
  int wo = blockIdx.x * 32 + threadIdx.y;
  int ho = blockIdx.y * 32 + threadIdx.x;
  float v = t[threadIdx.x][threadIdx.y];
  size_t o = ((size_t)b * 1024 + wo) * 1024 + ho;
  if (out_bf16) ((u16*)out)[o] = f2bf(v);
  else ((float*)out)[o] = v;
}

// LayerNorm over 1024, f32 in -> bf16 out. one block per row.
__global__ __launch_bounds__(256) void ln_kernel(const float* __restrict__ x,
                                                 const float* __restrict__ g,
                                                 const float* __restrict__ b,
                                                 u16* __restrict__ out)
{
  int row = blockIdx.x, tid = threadIdx.x;
  float4 v = ((const float4*)(x + (size_t)row * 1024))[tid];
  float s = v.x + v.y + v.z + v.w;
  float s2 = v.x * v.x + v.y * v.y + v.z * v.z + v.w * v.w;
#pragma unroll
  for (int o = 32; o; o >>= 1) { s += __shfl_down(s, o); s2 += __shfl_down(s2, o); }
  __shared__ float rs[4], rs2[4];
  int wid = tid >> 6, lane = tid & 63;
  if (lane == 0) { rs[wid] = s; rs2[wid] = s2; }
  __syncthreads();
  s = rs[0] + rs[1] + rs[2] + rs[3];
  s2 = rs2[0] + rs2[1] + rs2[2] + rs2[3];
  float mean = s * (1.f / 1024.f);
  float var = s2 * (1.f / 1024.f) - mean * mean;
  float rstd = rsqrtf(var + 1e-5f);
  float4 gv = ((const float4*)g)[tid];
  float4 bv = ((const float4*)b)[tid];
  ushort4 o;
  o.x = f2bf((v.x - mean) * rstd * gv.x + bv.x);
  o.y = f2bf((v.y - mean) * rstd * gv.y + bv.y);
  o.z = f2bf((v.z - mean) * rstd * gv.z + bv.z);
  o.w = f2bf((v.w - mean) * rstd * gv.w + bv.w);
  ((ushort4*)out)[(size_t)row * 256 + tid] = o;
}

// depthwise conv k=3 pad=1 along t (rows within each batch of 1024). bf16 in/out.
__global__ __launch_bounds__(128) void dwconv_kernel(const u16* __restrict__ in,
                                                     const float* __restrict__ wc,
                                                     u16* __restrict__ out)
{
  int row = blockIdx.x;     // b*1024 + t
  int t = row & 1023;
  int c0 = threadIdx.x * 8;
  const u16* r0 = in + (size_t)row * 1024 + c0;
  u16x8 zv = {0, 0, 0, 0, 0, 0, 0, 0};
  u16x8 xm = zv, xp = zv;
  if (t > 0) xm = *(const u16x8*)(r0 - 1024);
  u16x8 xc = *(const u16x8*)r0;
  if (t < 1023) xp = *(const u16x8*)(r0 + 1024);
  u16x8 o;
#pragma unroll
  for (int j = 0; j < 8; ++j) {
    int c = c0 + j;
    float v = bf2f(xm[j]) * wc[c * 3 + 0] + bf2f(xc[j]) * wc[c * 3 + 1] + bf2f(xp[j]) * wc[c * 3 + 2];
    o[j] = f2bf(v);
  }
  *(u16x8*)(out + (size_t)row * 1024 + c0) = o;
}

// depthwise conv + transposed store: out[(b*4+c/256)][c%256][t] = conv(in[b][t][c])
__global__ __launch_bounds__(1024) void dwconv_t_kernel(const u16* __restrict__ in,
                                                        const float* __restrict__ wc,
                                                        u16* __restrict__ out)
{
  __shared__ float tile[32][33];
  int b = blockIdx.z;
  int t = blockIdx.x * 32 + threadIdx.y;
  int c = blockIdx.y * 32 + threadIdx.x;
  size_t base = ((size_t)b * 1024 + t) * 1024 + c;
  float xm = (t > 0) ? bf2f(in[base - 1024]) : 0.f;
  float xc = bf2f(in[base]);
  float xp = (t < 1023) ? bf2f(in[base + 1024]) : 0.f;
  tile[threadIdx.y][threadIdx.x] = xm * wc[c * 3 + 0] + xc * wc[c * 3 + 1] + xp * wc[c * 3 + 2];
  __syncthreads();
  int c2 = blockIdx.y * 32 + threadIdx.y;
  int t2 = blockIdx.x * 32 + threadIdx.x;
  int z = b * 4 + (c2 >> 8);
  out[((size_t)z * 256 + (c2 & 255)) * 1024 + t2] = f2bf(tile[threadIdx.x][threadIdx.y]);
}

// row softmax over 1024, f32 in -> bf16 out
__global__ __launch_bounds__(256) void softmax_kernel(const float* __restrict__ qk,
                                                      u16* __restrict__ P)
{
  size_t row = blockIdx.x;
  int tid = threadIdx.x;
  float4 v = ((const float4*)(qk + row * 1024))[tid];
  float m = fmaxf(fmaxf(v.x, v.y), fmaxf(v.z, v.w));
#pragma unroll
  for (int o = 32; o; o >>= 1) m = fmaxf(m, __shfl_down(m, o));
  __shared__ float red[4];
  int wid = tid >> 6, lane = tid & 63;
  if (lane == 0) red[wid] = m;
  __syncthreads();
  m = fmaxf(fmaxf(red[0], red[1]), fmaxf(red[2], red[3]));
  float e0 = __expf(v.x - m), e1 = __expf(v.y - m), e2 = __expf(v.z - m), e3 = __expf(v.w - m);
  float s = e0 + e1 + e2 + e3;
#pragma unroll
  for (int o = 32; o; o >>= 1) s += __shfl_down(s, o);
  __syncthreads();
  if (lane == 0) red[wid] = s;
  __syncthreads();
  s = red[0] + red[1] + red[2] + red[3];
  float rinv = 1.f / s;
  ushort4 o;
  o.x = f2bf(e0 * rinv); o.y = f2bf(e1 * rinv); o.z = f2bf(e2 * rinv); o.w = f2bf(e3 * rinv);
  ((ushort4*)P)[row * 256 + tid] = o;
}

__global__ __launch_bounds__(256) void cast_kernel(const float* __restrict__ in,
                                                   u16* __restrict__ out, int n4)
{
  int i = blockIdx.x * 256 + threadIdx.x;
  if (i < n4) {
    float4 v = ((const float4*)in)[i];
    ushort4 o;
    o.x = f2bf(v.x); o.y = f2bf(v.y); o.z = f2bf(v.z); o.w = f2bf(v.w);
    ((ushort4*)out)[i] = o;
  }
}

// pw [256][1024] f32 -> pwT [1024][256] bf16
__global__ __launch_bounds__(1024) void pwt_kernel(const float* __restrict__ pw,
                                                   u16* __restrict__ pwT)
{
  __shared__ float tile[32][33];
  int d = blockIdx.y * 32 + threadIdx.y;
  int t = blockIdx.x * 32 + threadIdx.x;
  tile[threadIdx.y][threadIdx.x] = pw[(size_t)d * 1024 + t];
  __syncthreads();
  int t2 = blockIdx.x * 32 + threadIdx.y;
  int d2 = blockIdx.y * 32 + threadIdx.x;
  pwT[(size_t)t2 * 256 + d2] = f2bf(tile[threadIdx.x][threadIdx.y]);
}

// out[b][h][w] = xs[b][w][h], f32
__global__ __launch_bounds__(1024) void tout_kernel(const float* __restrict__ xs,
                                                    float* __restrict__ out)
{
  __shared__ float tile[32][33];
  int b = blockIdx.z;
  int w = blockIdx.x * 32 + threadIdx.y;
  int h = blockIdx.y * 32 + threadIdx.x;
  tile[threadIdx.y][threadIdx.x] = xs[((size_t)b * 1024 + w) * 1024 + h];
  __syncthreads();
  int h2 = blockIdx.y * 32 + threadIdx.y;
  int w2 = blockIdx.x * 32 + threadIdx.x;
  out[((size_t)b * 1024 + h2) * 1024 + w2] = tile[threadIdx.x][threadIdx.y];
}

static void run_attn(hipStream_t stream, float* xs, const u16* qsrc, const u16* kvsrc,
                     u16* Qraw, u16* Kraw, u16* Vraw, u16* Qc, u16* Kc, u16* Vt,
                     u16* P, u16* Am,
                     const u16* wq, const u16* wk, const u16* wv, const u16* wo, const u16* pwt,
                     const float* qc, const float* kc, const float* vc,
                     const float* prevqk, float* qko)
{
  dim3 blk(256);
  // QKV projections: M=4096, N=1024, K=1024
  gemm_core<EPI_BF16, false><<<dim3(8, 32, 1), blk, 0, stream>>>(
      qsrc, 0, 0, 1024, nullptr, 0, wq, 0, 0, 1024, nullptr, 0, 0, 0,
      1024, 0, Qraw, 0, 0, 1024, nullptr, 0, 0, 1.f);
  gemm_core<EPI_BF16, false><<<dim3(8, 32, 1), blk, 0, stream>>>(
      kvsrc, 0, 0, 1024, nullptr, 0, wk, 0, 0, 1024, nullptr, 0, 0, 0,
      1024, 0, Kraw, 0, 0, 1024, nullptr, 0, 0, 1.f);
  gemm_core<EPI_BF16, false><<<dim3(8, 32, 1), blk, 0, stream>>>(
      kvsrc, 0, 0, 1024, nullptr, 0, wv, 0, 0, 1024, nullptr, 0, 0, 0,
      1024, 0, Vraw, 0, 0, 1024, nullptr, 0, 0, 1.f);
  dwconv_kernel<<<4096, 128, 0, stream>>>(Qraw, qc, Qc);
  dwconv_kernel<<<4096, 128, 0, stream>>>(Kraw, kc, Kc);
  dwconv_t_kernel<<<dim3(32, 32, 4), dim3(32, 32), 0, stream>>>(Vraw, vc, Vt);
  // qk = (Q Kt + pwT Qt)/32 + prev, K=512 split at 256. 16 batches (b,n).
  gemm_core<EPI_QK, true><<<dim3(8, 8, 16), blk, 0, stream>>>(
      Qc, 1048576, 256, 1024, pwt, 256,
      Kc, 1048576, 256, 1024, Qc, 1048576, 256, 1024,
      512, 256, qko, 4194304, 1048576, 1024, prevqk, 1048576, 1024, 0.03125f);
  softmax_kernel<<<16384, 256, 0, stream>>>(qko, P);
  // PV: per z, [1024x1024]x[1024x256]
  gemm_core<EPI_BF16, false><<<dim3(2, 8, 16), blk, 0, stream>>>(
      P, 4194304, 1048576, 1024, nullptr, 0, Vt, 1048576, 262144, 1024, nullptr, 0, 0, 0,
      1024, 0, Am, 1048576, 256, 1024, nullptr, 0, 0, 1.f);
  // O-proj + residual add into xs (f32)
  gemm_core<EPI_ADDF32, false><<<dim3(8, 32, 1), blk, 0, stream>>>(
      Am, 0, 0, 1024, nullptr, 0, wo, 0, 0, 1024, nullptr, 0, 0, 0,
      1024, 0, xs, 0, 0, 1024, nullptr, 0, 0, 1.f);
}

extern "C" void kernel_launch(void* const* d_in, const int* in_sizes, int n_in,
                              void* d_out, int out_size, void* d_ws, size_t ws_size,
                              hipStream_t stream)
{
  (void)in_sizes; (void)n_in; (void)out_size; (void)ws_size;
  const float* x    = (const float*)d_in[0];
  const float* memp = (const float*)d_in[1];
  const float* pqk1 = (const float*)d_in[2];
  const float* pqk2 = (const float*)d_in[3];
  const float* ip_w = (const float*)d_in[4];
  const float* ip_b = (const float*)d_in[5];
  const float* mp_w = (const float*)d_in[6];
  const float* mp_b = (const float*)d_in[7];
  const float* ln1g = (const float*)d_in[8];
  const float* ln1b = (const float*)d_in[9];
  const float* ln2g = (const float*)d_in[10];
  const float* ln2b = (const float*)d_in[11];
  const float* ln3g = (const float*)d_in[12];
  const float* ln3b = (const float*)d_in[13];
  const float* a1qw = (const float*)d_in[14];
  const float* a1qc = (const float*)d_in[15];
  const float* a1kw = (const float*)d_in[16];
  const float* a1kc = (const float*)d_in[17];
  const float* a1vw = (const float*)d_in[18];
  const float* a1vc = (const float*)d_in[19];
  const float* a1ow = (const float*)d_in[20];
  const float* a1pw = (const float*)d_in[21];
  const float* a2qw = (const float*)d_in[22];
  const float* a2qc = (const float*)d_in[23];
  const float* a2kw = (const float*)d_in[24];
  const float* a2kc = (const float*)d_in[25];
  const float* a2vw = (const float*)d_in[26];
  const float* a2vc = (const float*)d_in[27];
  const float* a2ow = (const float*)d_in[28];
  const float* a2pw = (const float*)d_in[29];
  const float* l1w  = (const float*)d_in[30];
  const float* l2w  = (const float*)d_in[31];

  float* outp = (float*)d_out;
  float* qk1o = outp + 4194304;    // [4][4][1024][1024]
  float* qk2o = outp + 20971520;

  const size_t MB = 1024 * 1024;
  char* W = (char*)d_ws;
  float* xs  = (float*)(W);             // 16MB f32 [4][1024w][1024h]
  u16* msb  = (u16*)(W + 16 * MB);      // 8MB bf16
  u16* xln  = (u16*)(W + 24 * MB);      // 8MB
  u16* Qraw = (u16*)(W + 32 * MB);      // 8MB
  u16* Kraw = (u16*)(W + 40 * MB);      // 8MB
  u16* Vraw = (u16*)(W + 48 * MB);      // 8MB
  u16* Qc   = (u16*)(W + 56 * MB);      // 8MB
  u16* Kc   = (u16*)(W + 64 * MB);      // 8MB
  u16* Vt   = (u16*)(W + 72 * MB);      // 8MB  [16][256][1024]
  u16* P    = (u16*)(W + 80 * MB);      // 32MB [16][1024][1024]
  u16* Am   = (u16*)(W + 112 * MB);     // 8MB
  u16* wq1  = (u16*)(W + 120 * MB);
  u16* wk1  = (u16*)(W + 122 * MB);
  u16* wv1  = (u16*)(W + 124 * MB);
  u16* wo1  = (u16*)(W + 126 * MB);
  u16* wq2  = (u16*)(W + 128 * MB);
  u16* wk2  = (u16*)(W + 130 * MB);
  u16* wv2  = (u16*)(W + 132 * MB);
  u16* wo2  = (u16*)(W + 134 * MB);
  u16* wl1  = (u16*)(W + 136 * MB);     // 4MB [2048][1024]
  u16* wl2  = (u16*)(W + 140 * MB);     // 4MB [1024][2048]
  u16* pwt1 = (u16*)(W + 144 * MB);     // 0.5MB [1024][256]
  u16* pwt2 = (u16*)(W + 144 * MB + 512 * 1024);
  u16* H1   = Qraw;                     // 16MB overlay on Qraw+Kraw (dead in FFN)

  // weight conversions
  cast_kernel<<<1024, 256, 0, stream>>>(a1qw, wq1, 262144);
  cast_kernel<<<1024, 256, 0, stream>>>(a1kw, wk1, 262144);
  cast_kernel<<<1024, 256, 0, stream>>>(a1vw, wv1, 262144);
  cast_kernel<<<1024, 256, 0, stream>>>(a1ow, wo1, 262144);
  cast_kernel<<<1024, 256, 0, stream>>>(a2qw, wq2, 262144);
  cast_kernel<<<1024, 256, 0, stream>>>(a2kw, wk2, 262144);
  cast_kernel<<<1024, 256, 0, stream>>>(a2vw, wv2, 262144);
  cast_kernel<<<1024, 256, 0, stream>>>(a2ow, wo2, 262144);
  cast_kernel<<<2048, 256, 0, stream>>>(l1w, wl1, 524288);
  cast_kernel<<<2048, 256, 0, stream>>>(l2w, wl2, 524288);
  pwt_kernel<<<dim3(32, 8, 1), dim3(32, 32), 0, stream>>>(a1pw, pwt1);
  pwt_kernel<<<dim3(32, 8, 1), dim3(32, 32), 0, stream>>>(a2pw, pwt2);

  // input projections
  proj_kernel<<<dim3(32, 32, 4), dim3(32, 32), 0, stream>>>(x, ip_w, ip_b, xs, 0);
  proj_kernel<<<dim3(32, 32, 4), dim3(32, 32), 0, stream>>>(memp, mp_w, mp_b, msb, 1);

  // attention 1 (self): q and kv both from LN1(xs)
  ln_kernel<<<4096, 256, 0, stream>>>(xs, ln1g, ln1b, xln);
  run_attn(stream, xs, xln, xln, Qraw, Kraw, Vraw, Qc, Kc, Vt, P, Am,
           wq1, wk1, wv1, wo1, pwt1, a1qc, a1kc, a1vc, pqk1, qk1o);

  // attention 2 (cross): q from LN2(xs), kv from ms
  ln_kernel<<<4096, 256, 0, stream>>>(xs, ln2g, ln2b, xln);
  run_attn(stream, xs, xln, msb, Qraw, Kraw, Vraw, Qc, Kc, Vt, P, Am,
           wq2, wk2, wv2, wo2, pwt2, a2qc, a2kc, a2vc, pqk2, qk2o);

  // FFN
  ln_kernel<<<4096, 256, 0, stream>>>(xs, ln3g, ln3b, xln);
  gemm_core<EPI_RELU2, false><<<dim3(16, 32, 1), dim3(256), 0, stream>>>(
      xln, 0, 0, 1024, nullptr, 0, wl1, 0, 0, 1024, nullptr, 0, 0, 0,
      1024, 0, H1, 0, 0, 2048, nullptr, 0, 0, 1.f);
  gemm_core<EPI_ADDF32, false><<<dim3(8, 32, 1), dim3(256), 0, stream>>>(
      H1, 0, 0, 2048, nullptr, 0, wl2, 0, 0, 2048, nullptr, 0, 0, 0,
      2048, 0, xs, 0, 0, 1024, nullptr, 0, 0, 1.f);

  // final transpose to out[b][1][bins][w]
  tout_kernel<<<dim3(32, 32, 4), dim3(32, 32), 0, stream>>>(xs, outp);
}

// Round 2
// 582.236 us; speedup vs baseline: 1.2316x; 1.2316x over previous
//
#include <hip/hip_runtime.h>
#include <stdint.h>

typedef unsigned short u16;
typedef __bf16 bfv8 __attribute__((ext_vector_type(8)));
typedef float f32x4 __attribute__((ext_vector_type(4)));
typedef unsigned short u16x8 __attribute__((ext_vector_type(8)));

#define DI __device__ __forceinline__

DI u16 f2bf(float f) {
  union { float f; unsigned u; } c; c.f = f;
  unsigned r = c.u + 0x7FFFu + ((c.u >> 16) & 1u);
  return (u16)(r >> 16);
}
DI float bf2f(u16 b) {
  union { unsigned u; float f; } c; c.u = ((unsigned)b) << 16;
  return c.f;
}

enum { EPI_BF16 = 0, EPI_RELU2 = 1, EPI_ADDF32 = 2, EPI_QK = 3 };

#define GLDS(g, l)                                                              \
  __builtin_amdgcn_global_load_lds((const __attribute__((address_space(1))) void*)(g), \
                                   (__attribute__((address_space(3))) void*)(l), 16, 0, 0)

#define VMCNT_BAR(N)                                        \
  do {                                                      \
    asm volatile("s_waitcnt vmcnt(" #N ")" ::: "memory");   \
    __builtin_amdgcn_sched_barrier(0);                      \
    __builtin_amdgcn_s_barrier();                           \
    __builtin_amdgcn_sched_barrier(0);                      \
  } while (0)

// C[m,n] = sum_k A[m,k]*B[n,k]. Tile 128x256, BK=64, 512 thr (8 waves 2Mx4N),
// 3-stage LDS pipeline with counted vmcnt (T3+T4) + setprio (T5).
// A source selectable per output-column block (n0>=asplit -> Akv) for fused QKV.
// KSPLIT: k>=ksp reads A2 (unbatched)/B2 (batched).
// LDS XOR swizzle identical to verified round-1 scheme: phys chunk (row,c)
// holds global chunk (row, c^(row&7)); reader applies same XOR.
template <int EPI, bool KSPLIT>
__global__ __launch_bounds__(512) void gemm256(
    const u16* __restrict__ Aq, const u16* __restrict__ Akv, int asplit,
    long a1q, long a1r, int lda1,
    const u16* __restrict__ A2, int lda2,
    const u16* __restrict__ B1, long b1q, long b1r, int ldb1,
    const u16* __restrict__ B2, long b2q, long b2r, int ldb2,
    int K, int ksp,
    void* __restrict__ Cv, long cq, long cr, int ldc,
    const float* __restrict__ extra, long eq, int lde,
    float scale)
{
  __shared__ __align__(16) u16 lds[3 * 24576];   // per stage: A 128x64 (8192) + B 256x64 (16384)
  const int tid = threadIdx.x;
  const int wid = tid >> 6, lane = tid & 63;
  const long zq = blockIdx.z >> 2, zr = blockIdx.z & 3;
  const int m0 = blockIdx.y * 128, n0 = blockIdx.x * 256;
  const u16* Ab = ((n0 >= asplit) ? Akv : Aq) + zq * a1q + zr * a1r;
  const u16* Bb = B1 + zq * b1q + zr * b1r;
  const u16* B2b = KSPLIT ? (B2 + zq * b2q + zr * b2r) : (const u16*)nullptr;
  const int wm = (wid >> 2) * 64, wn = (wid & 3) * 64;
  const int fr = lane & 15, fq = lane >> 4;

  f32x4 acc[4][4];
#pragma unroll
  for (int i = 0; i < 4; ++i)
#pragma unroll
    for (int j = 0; j < 4; ++j)
      acc[i][j] = (f32x4){0.f, 0.f, 0.f, 0.f};

  const int nt = K >> 6;

  auto STAGE = [&](int tt, int sb) {
    const int k0 = tt << 6;
    u16* Ld = &lds[sb * 24576];
    const u16* Asrc; int la; const u16* Bsrc; int lb;
    if (!KSPLIT || k0 < ksp) { Asrc = Ab + k0; la = lda1; Bsrc = Bb + k0; lb = ldb1; }
    else { Asrc = A2 + (k0 - ksp); la = lda2; Bsrc = B2b + (k0 - ksp); lb = ldb2; }
#pragma unroll
    for (int l = 0; l < 2; ++l) {               // A: 1024 chunks / 512 thr
      int idx = (l << 9) + tid;
      int row = idx >> 3;
      int sc = ((idx & 7) ^ (row & 7)) << 3;    // pre-swizzled global column
      GLDS(Asrc + (size_t)(m0 + row) * la + sc,
           Ld + (((l << 3) + wid) << 9));       // (l*512 + wid*64) chunks * 8 elems
    }
#pragma unroll
    for (int l = 0; l < 4; ++l) {               // B: 2048 chunks / 512 thr
      int idx = (l << 9) + tid;
      int row = idx >> 3;
      int sc = ((idx & 7) ^ (row & 7)) << 3;
      GLDS(Bsrc + (size_t)(n0 + row) * lb + sc,
           Ld + 8192 + (((l << 3) + wid) << 9));
    }
  };

  auto COMPUTE = [&](int cb) {
    const u16* As = &lds[cb * 24576];
    const u16* Bs = As + 8192;
#pragma unroll
    for (int ks = 0; ks < 2; ++ks) {
      bfv8 av[4];
#pragma unroll
      for (int i = 0; i < 4; ++i) {
        int ra = wm + i * 16 + fr;
        int ca = (((ks << 2) + fq) ^ (ra & 7)) << 3;
        av[i] = *(const bfv8*)&As[(ra << 6) + ca];
      }
#pragma unroll
      for (int nh = 0; nh < 2; ++nh) {
        bfv8 bv[2];
#pragma unroll
        for (int j = 0; j < 2; ++j) {
          int rb = wn + (nh << 5) + (j << 4) + fr;
          int cb2 = (((ks << 2) + fq) ^ (rb & 7)) << 3;
          bv[j] = *(const bfv8*)&Bs[(rb << 6) + cb2];
        }
        __builtin_amdgcn_s_setprio(1);
#pragma unroll
        for (int i = 0; i < 4; ++i) {
          acc[i][(nh << 1)] = __builtin_amdgcn_mfma_f32_16x16x32_bf16(av[i], bv[0], acc[i][(nh << 1)], 0, 0, 0);
          acc[i][(nh << 1) + 1] = __builtin_amdgcn_mfma_f32_16x16x32_bf16(av[i], bv[1], acc[i][(nh << 1) + 1], 0, 0, 0);
        }
        __builtin_amdgcn_s_setprio(0);
      }
    }
  };

  STAGE(0, 0);
  STAGE(1, 1);
  VMCNT_BAR(6);                 // tile 0 landed (tile 1's 6 loads may remain in flight)
  int cur = 0;
  for (int t = 0; t < nt; ++t) {
    if (t + 2 < nt) {
      int stg = cur + 2; if (stg >= 3) stg -= 3;
      STAGE(t + 2, stg);        // issue t+2 before computing t: latency hides under MFMA
      COMPUTE(cur);
      VMCNT_BAR(6);             // t+1 landed; t+2's 6 loads stay in flight across barrier
    } else if (t + 1 < nt) {
      COMPUTE(cur);
      VMCNT_BAR(0);             // drain last prefetch
    } else {
      COMPUTE(cur);
    }
    cur = (cur == 2) ? 0 : cur + 1;
  }

  if constexpr (EPI == EPI_BF16 || EPI == EPI_RELU2) {
    u16* Cb = (u16*)Cv + zq * cq + zr * cr;
#pragma unroll
    for (int i = 0; i < 4; ++i)
#pragma unroll
      for (int j = 0; j < 4; ++j)
#pragma unroll
        for (int r = 0; r < 4; ++r) {
          int row = m0 + wm + i * 16 + (fq << 2) + r;
          int col = n0 + wn + j * 16 + fr;
          float v = acc[i][j][r];
          if constexpr (EPI == EPI_RELU2) { v = fmaxf(v, 0.f); v = v * v; }
          Cb[(size_t)row * ldc + col] = f2bf(v);
        }
  } else if constexpr (EPI == EPI_ADDF32) {
    float* Cb = (float*)Cv + zq * cq + zr * cr;
#pragma unroll
    for (int i = 0; i < 4; ++i)
#pragma unroll
      for (int j = 0; j < 4; ++j)
#pragma unroll
        for (int r = 0; r < 4; ++r) {
          int row = m0 + wm + i * 16 + (fq << 2) + r;
          int col = n0 + wn + j * 16 + fr;
          Cb[(size_t)row * ldc + col] += acc[i][j][r];
        }
  } else {  // EPI_QK
    float* Cb = (float*)Cv + zq * cq + zr * cr;
    const float* Eb = extra + (size_t)blockIdx.z * eq;
#pragma unroll
    for (int i = 0; i < 4; ++i)
#pragma unroll
      for (int j = 0; j < 4; ++j)
#pragma unroll
        for (int r = 0; r < 4; ++r) {
          int row = m0 + wm + i * 16 + (fq << 2) + r;
          int col = n0 + wn + j * 16 + fr;
          Cb[(size_t)row * ldc + col] = acc[i][j][r] * scale + Eb[(size_t)row * lde + col];
        }
  }
}

// xs[b,w,h] = sum_c x[b,c,h,w]*w8[c] + bias ; out f32 or bf16
__global__ __launch_bounds__(1024) void proj_kernel(const float* __restrict__ x,
                                                    const float* __restrict__ w8,
                                                    const float* __restrict__ bias,
                                                    void* __restrict__ out, int out_bf16)
{
  __shared__ float t[32][33];
  int b = blockIdx.z;
  int h = blockIdx.y * 32 + threadIdx.y;
  int w = blockIdx.x * 32 + threadIdx.x;
  float acc = bias[0];
#pragma unroll
  for (int c = 0; c < 8; ++c)
    acc += x[(((size_t)b * 8 + c) * 1024 + h) * 1024 + w] * w8[c];
  t[threadIdx.y][threadIdx.x] = acc;
  __syncthreads();
  int wo = blockIdx.x * 32 + threadIdx.y;
  int ho = blockIdx.y * 32 + threadIdx.x;
  float v = t[threadIdx.x][threadIdx.y];
  size_t o = ((size_t)b * 1024 + wo) * 1024 + ho;
  if (out_bf16) ((u16*)out)[o] = f2bf(v);
  else ((float*)out)[o] = v;
}

// LayerNorm over 1024, f32 in -> bf16 out. one block per row.
__global__ __launch_bounds__(256) void ln_kernel(const float* __restrict__ x,
                                                 const float* __restrict__ g,
                                                 const float* __restrict__ b,
                                                 u16* __restrict__ out)
{
  int row = blockIdx.x, tid = threadIdx.x;
  float4 v = ((const float4*)(x + (size_t)row * 1024))[tid];
  float s = v.x + v.y + v.z + v.w;
  float s2 = v.x * v.x + v.y * v.y + v.z * v.z + v.w * v.w;
#pragma unroll
  for (int o = 32; o; o >>= 1) { s += __shfl_down(s, o); s2 += __shfl_down(s2, o); }
  __shared__ float rs[4], rs2[4];
  int wid = tid >> 6, lane = tid & 63;
  if (lane == 0) { rs[wid] = s; rs2[wid] = s2; }
  __syncthreads();
  s = rs[0] + rs[1] + rs[2] + rs[3];
  s2 = rs2[0] + rs2[1] + rs2[2] + rs2[3];
  float mean = s * (1.f / 1024.f);
  float var = s2 * (1.f / 1024.f) - mean * mean;
  float rstd = rsqrtf(var + 1e-5f);
  float4 gv = ((const float4*)g)[tid];
  float4 bv = ((const float4*)b)[tid];
  ushort4 o;
  o.x = f2bf((v.x - mean) * rstd * gv.x + bv.x);
  o.y = f2bf((v.y - mean) * rstd * gv.y + bv.y);
  o.z = f2bf((v.z - mean) * rstd * gv.z + bv.z);
  o.w = f2bf((v.w - mean) * rstd * gv.w + bv.w);
  ((ushort4*)out)[(size_t)row * 256 + tid] = o;
}

// depthwise conv k=3 pad=1 along t for Q (sel=0) and K (sel=1) from fused QKV buffer.
__global__ __launch_bounds__(128) void dwconv_qk_kernel(const u16* __restrict__ qkv,
                                                        const float* __restrict__ qc,
                                                        const float* __restrict__ kc,
                                                        u16* __restrict__ Qc,
                                                        u16* __restrict__ Kc)
{
  int sel = blockIdx.y;
  int row = blockIdx.x;     // b*1024 + t
  int t = row & 1023;
  int c0 = threadIdx.x * 8;
  const u16* r0 = qkv + (size_t)row * 3072 + (sel << 10) + c0;
  const float* wc = sel ? kc : qc;
  u16* dst = (sel ? Kc : Qc) + (size_t)row * 1024 + c0;
  u16x8 zv = {0, 0, 0, 0, 0, 0, 0, 0};
  u16x8 xm = zv, xp = zv;
  if (t > 0) xm = *(const u16x8*)(r0 - 3072);
  u16x8 xc = *(const u16x8*)r0;
  if (t < 1023) xp = *(const u16x8*)(r0 + 3072);
  u16x8 o;
#pragma unroll
  for (int j = 0; j < 8; ++j) {
    int c = c0 + j;
    float v = bf2f(xm[j]) * wc[c * 3 + 0] + bf2f(xc[j]) * wc[c * 3 + 1] + bf2f(xp[j]) * wc[c * 3 + 2];
    o[j] = f2bf(v);
  }
  *(u16x8*)dst = o;
}

// depthwise conv + transposed store for V: out[(b*4+c/256)][c%256][t] from qkv col 2048+c
__global__ __launch_bounds__(1024) void dwconv_t_kernel(const u16* __restrict__ qkv,
                                                        const float* __restrict__ wc,
                                                        u16* __restrict__ out)
{
  __shared__ float tile[32][33];
  int b = blockIdx.z;
  int t = blockIdx.x * 32 + threadIdx.y;
  int c = blockIdx.y * 32 + threadIdx.x;
  size_t base = ((size_t)b * 1024 + t) * 3072 + 2048 + c;
  float xm = (t > 0) ? bf2f(qkv[base - 3072]) : 0.f;
  float xc = bf2f(qkv[base]);
  float xp = (t < 1023) ? bf2f(qkv[base + 3072]) : 0.f;
  tile[threadIdx.y][threadIdx.x] = xm * wc[c * 3 + 0] + xc * wc[c * 3 + 1] + xp * wc[c * 3 + 2];
  __syncthreads();
  int c2 = blockIdx.y * 32 + threadIdx.y;
  int t2 = blockIdx.x * 32 + threadIdx.x;
  int z = b * 4 + (c2 >> 8);
  out[((size_t)z * 256 + (c2 & 255)) * 1024 + t2] = f2bf(tile[threadIdx.x][threadIdx.y]);
}

// row softmax over 1024, f32 in -> bf16 out
__global__ __launch_bounds__(256) void softmax_kernel(const float* __restrict__ qk,
                                                      u16* __restrict__ P)
{
  size_t row = blockIdx.x;
  int tid = threadIdx.x;
  float4 v = ((const float4*)(qk + row * 1024))[tid];
  float m = fmaxf(fmaxf(v.x, v.y), fmaxf(v.z, v.w));
#pragma unroll
  for (int o = 32; o; o >>= 1) m = fmaxf(m, __shfl_down(m, o));
  __shared__ float red[4];
  int wid = tid >> 6, lane = tid & 63;
  if (lane == 0) red[wid] = m;
  __syncthreads();
  m = fmaxf(fmaxf(red[0], red[1]), fmaxf(red[2], red[3]));
  float e0 = __expf(v.x - m), e1 = __expf(v.y - m), e2 = __expf(v.z - m), e3 = __expf(v.w - m);
  float s = e0 + e1 + e2 + e3;
#pragma unroll
  for (int o = 32; o; o >>= 1) s += __shfl_down(s, o);
  __syncthreads();
  if (lane == 0) red[wid] = s;
  __syncthreads();
  s = red[0] + red[1] + red[2] + red[3];
  float rinv = 1.f / s;
  ushort4 o;
  o.x = f2bf(e0 * rinv); o.y = f2bf(e1 * rinv); o.z = f2bf(e2 * rinv); o.w = f2bf(e3 * rinv);
  ((ushort4*)P)[row * 256 + tid] = o;
}

// 12 fused f32->bf16 casts of 1M elements each (weight prep, one launch)
struct CastJobs { const float* s[12]; u16* d[12]; };
__global__ __launch_bounds__(256) void cast12_kernel(CastJobs J)
{
  int j = blockIdx.y;
  int i = blockIdx.x * 256 + threadIdx.x;   // 262144 float4 per job
  float4 v = ((const float4*)J.s[j])[i];
  ushort4 o;
  o.x = f2bf(v.x); o.y = f2bf(v.y); o.z = f2bf(v.z); o.w = f2bf(v.w);
  ((ushort4*)J.d[j])[i] = o;
}

// pw [256][1024] f32 -> pwT [1024][256] bf16
__global__ __launch_bounds__(1024) void pwt_kernel(const float* __restrict__ pw,
                                                   u16* __restrict__ pwT)
{
  __shared__ float tile[32][33];
  int d = blockIdx.y * 32 + threadIdx.y;
  int t = blockIdx.x * 32 + threadIdx.x;
  tile[threadIdx.y][threadIdx.x] = pw[(size_t)d * 1024 + t];
  __syncthreads();
  int t2 = blockIdx.x * 32 + threadIdx.y;
  int d2 = blockIdx.y * 32 + threadIdx.x;
  pwT[(size_t)t2 * 256 + d2] = f2bf(tile[threadIdx.x][threadIdx.y]);
}

// out[b][h][w] = xs[b][w][h], f32
__global__ __launch_bounds__(1024) void tout_kernel(const float* __restrict__ xs,
                                                    float* __restrict__ out)
{
  __shared__ float tile[32][33];
  int b = blockIdx.z;
  int w = blockIdx.x * 32 + threadIdx.y;
  int h = blockIdx.y * 32 + threadIdx.x;
  tile[threadIdx.y][threadIdx.x] = xs[((size_t)b * 1024 + w) * 1024 + h];
  __syncthreads();
  int h2 = blockIdx.y * 32 + threadIdx.y;
  int w2 = blockIdx.x * 32 + threadIdx.x;
  out[((size_t)b * 1024 + h2) * 1024 + w2] = tile[threadIdx.x][threadIdx.y];
}

static void run_attn(hipStream_t stream, float* xs, const u16* qsrc, const u16* kvsrc, int asplit,
                     u16* QKVraw, u16* Qc, u16* Kc, u16* Vt, u16* P, u16* Am,
                     const u16* wqkv, const u16* wo, const u16* pwt,
                     const float* qc, const float* kc, const float* vc,
                     const float* prevqk, float* qko)
{
  dim3 blk(512);
  // fused QKV projection: M=4096, N=3072, K=1024. A per-column-block select.
  gemm256<EPI_BF16, false><<<dim3(12, 32, 1), blk, 0, stream>>>(
      qsrc, kvsrc, asplit, 0, 0, 1024, nullptr, 0,
      wqkv, 0, 0, 1024, nullptr, 0, 0, 0,
      1024, 0, QKVraw, 0, 0, 3072, nullptr, 0, 0, 1.f);
  dwconv_qk_kernel<<<dim3(4096, 2), 128, 0, stream>>>(QKVraw, qc, kc, Qc, Kc);
  dwconv_t_kernel<<<dim3(32, 32, 4), dim3(32, 32), 0, stream>>>(QKVraw, vc, Vt);
  // qk = (Q Kt + pwT Qt)/32 + prev, K=512 split at 256. 16 batches (b,n).
  gemm256<EPI_QK, true><<<dim3(4, 8, 16), blk, 0, stream>>>(
      Qc, Qc, 1 << 30, 1048576, 256, 1024, pwt, 256,
      Kc, 1048576, 256, 1024, Qc, 1048576, 256, 1024,
      512, 256, qko, 4194304, 1048576, 1024, prevqk, 1048576, 1024, 0.03125f);
  softmax_kernel<<<16384, 256, 0, stream>>>(qko, P);
  // PV: per z, [1024x1024]x[1024x256]
  gemm256<EPI_BF16, false><<<dim3(1, 8, 16), blk, 0, stream>>>(
      P, P, 1 << 30, 4194304, 1048576, 1024, nullptr, 0,
      Vt, 1048576, 262144, 1024, nullptr, 0, 0, 0,
      1024, 0, Am, 1048576, 256, 1024, nullptr, 0, 0, 1.f);
  // O-proj + residual add into xs (f32)
  gemm256<EPI_ADDF32, false><<<dim3(4, 32, 1), blk, 0, stream>>>(
      Am, Am, 1 << 30, 0, 0, 1024, nullptr, 0,
      wo, 0, 0, 1024, nullptr, 0, 0, 0,
      1024, 0, xs, 0, 0, 1024, nullptr, 0, 0, 1.f);
}

extern "C" void kernel_launch(void* const* d_in, const int* in_sizes, int n_in,
                              void* d_out, int out_size, void* d_ws, size_t ws_size,
                              hipStream_t stream)
{
  (void)in_sizes; (void)n_in; (void)out_size; (void)ws_size;
  const float* x    = (const float*)d_in[0];
  const float* memp = (const float*)d_in[1];
  const float* pqk1 = (const float*)d_in[2];
  const float* pqk2 = (const float*)d_in[3];
  const float* ip_w = (const float*)d_in[4];
  const float* ip_b = (const float*)d_in[5];
  const float* mp_w = (const float*)d_in[6];
  const float* mp_b = (const float*)d_in[7];
  const float* ln1g = (const float*)d_in[8];
  const float* ln1b = (const float*)d_in[9];
  const float* ln2g = (const float*)d_in[10];
  const float* ln2b = (const float*)d_in[11];
  const float* ln3g = (const float*)d_in[12];
  const float* ln3b = (const float*)d_in[13];
  const float* a1qw = (const float*)d_in[14];
  const float* a1qc = (const float*)d_in[15];
  const float* a1kw = (const float*)d_in[16];
  const float* a1kc = (const float*)d_in[17];
  const float* a1vw = (const float*)d_in[18];
  const float* a1vc = (const float*)d_in[19];
  const float* a1ow = (const float*)d_in[20];
  const float* a1pw = (const float*)d_in[21];
  const float* a2qw = (const float*)d_in[22];
  const float* a2qc = (const float*)d_in[23];
  const float* a2kw = (const float*)d_in[24];
  const float* a2kc = (const float*)d_in[25];
  const float* a2vw = (const float*)d_in[26];
  const float* a2vc = (const float*)d_in[27];
  const float* a2ow = (const float*)d_in[28];
  const float* a2pw = (const float*)d_in[29];
  const float* l1w  = (const float*)d_in[30];
  const float* l2w  = (const float*)d_in[31];

  float* outp = (float*)d_out;
  float* qk1o = outp + 4194304;    // [4][4][1024][1024]
  float* qk2o = outp + 20971520;

  const size_t MB = 1024 * 1024;
  char* W = (char*)d_ws;
  float* xs   = (float*)(W);             // 16MB f32 [4][1024w][1024h]
  u16* msb    = (u16*)(W + 16 * MB);     // 8MB bf16
  u16* xln    = (u16*)(W + 24 * MB);     // 8MB
  u16* QKVraw = (u16*)(W + 32 * MB);     // 24MB [4096][3072]
  u16* Qc     = (u16*)(W + 56 * MB);     // 8MB
  u16* Kc     = (u16*)(W + 64 * MB);     // 8MB
  u16* Vt     = (u16*)(W + 72 * MB);     // 8MB  [16][256][1024]
  u16* P      = (u16*)(W + 80 * MB);     // 32MB [16][1024][1024]
  u16* Am     = (u16*)(W + 112 * MB);    // 8MB
  u16* wqkv1  = (u16*)(W + 120 * MB);    // 6MB [3072][1024]
  u16* wqkv2  = (u16*)(W + 126 * MB);    // 6MB
  u16* wo1    = (u16*)(W + 132 * MB);    // 2MB
  u16* wo2    = (u16*)(W + 134 * MB);    // 2MB
  u16* wl1    = (u16*)(W + 136 * MB);    // 4MB [2048][1024]
  u16* wl2    = (u16*)(W + 140 * MB);    // 4MB [1024][2048]
  u16* pwt1   = (u16*)(W + 144 * MB);    // 0.5MB [1024][256]
  u16* pwt2   = (u16*)(W + 144 * MB + 512 * 1024);
  u16* H1     = QKVraw;                  // 16MB overlay (dead in FFN)

  // weight prep: one fused cast launch + 2 pw transposes
  CastJobs J;
  J.s[0] = a1qw; J.d[0] = wqkv1;
  J.s[1] = a1kw; J.d[1] = wqkv1 + 1048576;
  J.s[2] = a1vw; J.d[2] = wqkv1 + 2097152;
  J.s[3] = a2qw; J.d[3] = wqkv2;
  J.s[4] = a2kw; J.d[4] = wqkv2 + 1048576;
  J.s[5] = a2vw; J.d[5] = wqkv2 + 2097152;
  J.s[6] = a1ow; J.d[6] = wo1;
  J.s[7] = a2ow; J.d[7] = wo2;
  J.s[8] = l1w;            J.d[8] = wl1;
  J.s[9] = l1w + 1048576;  J.d[9] = wl1 + 1048576;
  J.s[10] = l2w;           J.d[10] = wl2;
  J.s[11] = l2w + 1048576; J.d[11] = wl2 + 1048576;
  cast12_kernel<<<dim3(1024, 12), 256, 0, stream>>>(J);
  pwt_kernel<<<dim3(32, 8, 1), dim3(32, 32), 0, stream>>>(a1pw, pwt1);
  pwt_kernel<<<dim3(32, 8, 1), dim3(32, 32), 0, stream>>>(a2pw, pwt2);

  // input projections
  proj_kernel<<<dim3(32, 32, 4), dim3(32, 32), 0, stream>>>(x, ip_w, ip_b, xs, 0);
  proj_kernel<<<dim3(32, 32, 4), dim3(32, 32), 0, stream>>>(memp, mp_w, mp_b, msb, 1);

  // attention 1 (self): q and kv both from LN1(xs)
  ln_kernel<<<4096, 256, 0, stream>>>(xs, ln1g, ln1b, xln);
  run_attn(stream, xs, xln, xln, 1 << 30, QKVraw, Qc, Kc, Vt, P, Am,
           wqkv1, wo1, pwt1, a1qc, a1kc, a1vc, pqk1, qk1o);

  // attention 2 (cross): q from LN2(xs), kv from ms
  ln_kernel<<<4096, 256, 0, stream>>>(xs, ln2g, ln2b, xln);
  run_attn(stream, xs, xln, msb, 1024, QKVraw, Qc, Kc, Vt, P, Am,
           wqkv2, wo2, pwt2, a2qc, a2kc, a2vc, pqk2, qk2o);

  // FFN
  ln_kernel<<<4096, 256, 0, stream>>>(xs, ln3g, ln3b, xln);
  gemm256<EPI_RELU2, false><<<dim3(8, 32, 1), dim3(512), 0, stream>>>(
      xln, xln, 1 << 30, 0, 0, 1024, nullptr, 0,
      wl1, 0, 0, 1024, nullptr, 0, 0, 0,
      1024, 0, H1, 0, 0, 2048, nullptr, 0, 0, 1.f);
  gemm256<EPI_ADDF32, false><<<dim3(4, 32, 1), dim3(512), 0, stream>>>(
      H1, H1, 1 << 30, 0, 0, 2048, nullptr, 0,
      wl2, 0, 0, 2048, nullptr, 0, 0, 0,
      2048, 0, xs, 0, 0, 1024, nullptr, 0, 0, 1.f);

  // final transpose to out[b][1][bins][w]
  tout_kernel<<<dim3(32, 32, 4), dim3(32, 32), 0, stream>>>(xs, outp);
}

// Round 3
// 579.850 us; speedup vs baseline: 1.2366x; 1.0041x over previous
//
#include <hip/hip_runtime.h>
#include <stdint.h>

typedef unsigned short u16;
typedef __bf16 bfv8 __attribute__((ext_vector_type(8)));
typedef float f32x4 __attribute__((ext_vector_type(4)));
typedef unsigned short u16x8 __attribute__((ext_vector_type(8)));

#define DI __device__ __forceinline__

DI u16 f2bf(float f) {
  union { float f; unsigned u; } c; c.f = f;
  unsigned r = c.u + 0x7FFFu + ((c.u >> 16) & 1u);
  return (u16)(r >> 16);
}
DI float bf2f(u16 b) {
  union { unsigned u; float f; } c; c.u = ((unsigned)b) << 16;
  return c.f;
}

enum { EPI_BF16 = 0, EPI_RELU2 = 1, EPI_ADDF32 = 2, EPI_QK = 3 };

#define GLDS(g, l)                                                              \
  __builtin_amdgcn_global_load_lds((const __attribute__((address_space(1))) void*)(g), \
                                   (__attribute__((address_space(3))) void*)(l), 16, 0, 0)

#define VMCNT_BAR(N)                                        \
  do {                                                      \
    asm volatile("s_waitcnt vmcnt(" #N ")" ::: "memory");   \
    __builtin_amdgcn_sched_barrier(0);                      \
    __builtin_amdgcn_s_barrier();                           \
    __builtin_amdgcn_sched_barrier(0);                      \
  } while (0)

#define BAR_ONLY()                                          \
  do {                                                      \
    __builtin_amdgcn_sched_barrier(0);                      \
    __builtin_amdgcn_s_barrier();                           \
    __builtin_amdgcn_sched_barrier(0);                      \
  } while (0)

// C[m,n] = sum_k A[m,k]*B[n,k]. Tile 128x256, BK=64, 512 thr (8 waves 2Mx4N),
// 3-stage LDS pipeline, counted vmcnt (T4), per-K-tile 2-phase interleave
// (half the prefetch loads issued inside each phase, barrier between phases)
// + setprio around MFMA clusters (T5).
// A source selectable per output-column block (n0>=asplit -> Akv) for fused QKV.
// KSPLIT: k>=ksp reads A2 (unbatched)/B2 (batched).
// LDS XOR swizzle: phys chunk (row,c) holds global chunk (row, c^(row&7)).
template <int EPI, bool KSPLIT>
__global__ __launch_bounds__(512) void gemm256(
    const u16* __restrict__ Aq, const u16* __restrict__ Akv, int asplit,
    long a1q, long a1r, int lda1,
    const u16* __restrict__ A2, int lda2,
    const u16* __restrict__ B1, long b1q, long b1r, int ldb1,
    const u16* __restrict__ B2, long b2q, long b2r, int ldb2,
    int K, int ksp,
    void* __restrict__ Cv, long cq, long cr, int ldc,
    const float* __restrict__ extra, long eq, int lde,
    float scale)
{
  __shared__ __align__(16) u16 lds[3 * 24576];   // per stage: A 128x64 (8192) + B 256x64 (16384)
  const int tid = threadIdx.x;
  const int wid = tid >> 6, lane = tid & 63;
  const long zq = blockIdx.z >> 2, zr = blockIdx.z & 3;
  const int m0 = blockIdx.y * 128, n0 = blockIdx.x * 256;
  const u16* Ab = ((n0 >= asplit) ? Akv : Aq) + zq * a1q + zr * a1r;
  const u16* Bb = B1 + zq * b1q + zr * b1r;
  const u16* B2b = KSPLIT ? (B2 + zq * b2q + zr * b2r) : (const u16*)nullptr;
  const int wm = (wid >> 2) * 64, wn = (wid & 3) * 64;
  const int fr = lane & 15, fq = lane >> 4;

  f32x4 acc[4][4];
#pragma unroll
  for (int i = 0; i < 4; ++i)
#pragma unroll
    for (int j = 0; j < 4; ++j)
      acc[i][j] = (f32x4){0.f, 0.f, 0.f, 0.f};

  const int nt = K >> 6;

  // half 0: A loads l=0,1 + B load l=0 (3 instrs). half 1: B loads l=1..3 (3 instrs).
  auto STAGE_HALF = [&](int tt, int sb, int half) {
    const int k0 = tt << 6;
    u16* Ld = &lds[sb * 24576];
    const u16* Asrc; int la; const u16* Bsrc; int lb;
    if (!KSPLIT || k0 < ksp) { Asrc = Ab + k0; la = lda1; Bsrc = Bb + k0; lb = ldb1; }
    else { Asrc = A2 + (k0 - ksp); la = lda2; Bsrc = B2b + (k0 - ksp); lb = ldb2; }
    if (half == 0) {
#pragma unroll
      for (int l = 0; l < 2; ++l) {
        int idx = (l << 9) + tid;
        int row = idx >> 3;
        int sc = ((idx & 7) ^ (row & 7)) << 3;
        GLDS(Asrc + (size_t)(m0 + row) * la + sc,
             Ld + (((l << 3) + wid) << 9));
      }
      {
        int idx = tid;
        int row = idx >> 3;
        int sc = ((idx & 7) ^ (row & 7)) << 3;
        GLDS(Bsrc + (size_t)(n0 + row) * lb + sc, Ld + 8192 + (wid << 9));
      }
    } else {
#pragma unroll
      for (int l = 1; l < 4; ++l) {
        int idx = (l << 9) + tid;
        int row = idx >> 3;
        int sc = ((idx & 7) ^ (row & 7)) << 3;
        GLDS(Bsrc + (size_t)(n0 + row) * lb + sc,
             Ld + 8192 + (((l << 3) + wid) << 9));
      }
    }
  };
  auto STAGE = [&](int tt, int sb) { STAGE_HALF(tt, sb, 0); STAGE_HALF(tt, sb, 1); };

  // one k-slice (ks in {0,1}) of the current tile: 8 ds_read_b128 + 16 MFMA
  auto COMPUTE_KS = [&](int cb, int ks) {
    const u16* As = &lds[cb * 24576];
    const u16* Bs = As + 8192;
    bfv8 av[4];
#pragma unroll
    for (int i = 0; i < 4; ++i) {
      int ra = wm + i * 16 + fr;
      int ca = (((ks << 2) + fq) ^ (ra & 7)) << 3;
      av[i] = *(const bfv8*)&As[(ra << 6) + ca];
    }
#pragma unroll
    for (int nh = 0; nh < 2; ++nh) {
      bfv8 bv[2];
#pragma unroll
      for (int j = 0; j < 2; ++j) {
        int rb = wn + (nh << 5) + (j << 4) + fr;
        int cb2 = (((ks << 2) + fq) ^ (rb & 7)) << 3;
        bv[j] = *(const bfv8*)&Bs[(rb << 6) + cb2];
      }
      __builtin_amdgcn_s_setprio(1);
#pragma unroll
      for (int i = 0; i < 4; ++i) {
        acc[i][(nh << 1)] = __builtin_amdgcn_mfma_f32_16x16x32_bf16(av[i], bv[0], acc[i][(nh << 1)], 0, 0, 0);
        acc[i][(nh << 1) + 1] = __builtin_amdgcn_mfma_f32_16x16x32_bf16(av[i], bv[1], acc[i][(nh << 1) + 1], 0, 0, 0);
      }
      __builtin_amdgcn_s_setprio(0);
    }
  };

  STAGE(0, 0);
  STAGE(1, 1);
  VMCNT_BAR(6);                 // tile 0 landed (tile 1's 6 loads may remain in flight)
  int cur = 0;
  for (int t = 0; t < nt; ++t) {
    if (t + 2 < nt) {
      int stg = cur + 2; if (stg >= 3) stg -= 3;
      // phase A: issue first half of t+2's loads, compute ks=0
      STAGE_HALF(t + 2, stg, 0);
      COMPUTE_KS(cur, 0);
      BAR_ONLY();
      // phase B: issue second half, compute ks=1
      STAGE_HALF(t + 2, stg, 1);
      COMPUTE_KS(cur, 1);
      VMCNT_BAR(6);             // t+1 landed; t+2's 6 loads stay in flight across barrier
    } else if (t + 1 < nt) {
      COMPUTE_KS(cur, 0);
      COMPUTE_KS(cur, 1);
      VMCNT_BAR(0);             // drain last prefetch
    } else {
      COMPUTE_KS(cur, 0);
      COMPUTE_KS(cur, 1);
    }
    cur = (cur == 2) ? 0 : cur + 1;
  }

  if constexpr (EPI == EPI_BF16 || EPI == EPI_RELU2) {
    u16* Cb = (u16*)Cv + zq * cq + zr * cr;
#pragma unroll
    for (int i = 0; i < 4; ++i)
#pragma unroll
      for (int j = 0; j < 4; ++j)
#pragma unroll
        for (int r = 0; r < 4; ++r) {
          int row = m0 + wm + i * 16 + (fq << 2) + r;
          int col = n0 + wn + j * 16 + fr;
          float v = acc[i][j][r];
          if constexpr (EPI == EPI_RELU2) { v = fmaxf(v, 0.f); v = v * v; }
          Cb[(size_t)row * ldc + col] = f2bf(v);
        }
  } else if constexpr (EPI == EPI_ADDF32) {
    float* Cb = (float*)Cv + zq * cq + zr * cr;
#pragma unroll
    for (int i = 0; i < 4; ++i)
#pragma unroll
      for (int j = 0; j < 4; ++j)
#pragma unroll
        for (int r = 0; r < 4; ++r) {
          int row = m0 + wm + i * 16 + (fq << 2) + r;
          int col = n0 + wn + j * 16 + fr;
          Cb[(size_t)row * ldc + col] += acc[i][j][r];
        }
  } else {  // EPI_QK
    float* Cb = (float*)Cv + zq * cq + zr * cr;
    const float* Eb = extra + (size_t)blockIdx.z * eq;
#pragma unroll
    for (int i = 0; i < 4; ++i)
#pragma unroll
      for (int j = 0; j < 4; ++j)
#pragma unroll
        for (int r = 0; r < 4; ++r) {
          int row = m0 + wm + i * 16 + (fq << 2) + r;
          int col = n0 + wn + j * 16 + fr;
          Cb[(size_t)row * ldc + col] = acc[i][j][r] * scale + Eb[(size_t)row * lde + col];
        }
  }
}

// fused input projection: z=b + 4*task. task0: x -> xs (f32). task1: mem -> msb (bf16).
__global__ __launch_bounds__(1024) void proj2_kernel(const float* __restrict__ x,
                                                     const float* __restrict__ memp,
                                                     const float* __restrict__ ipw,
                                                     const float* __restrict__ ipb,
                                                     const float* __restrict__ mpw,
                                                     const float* __restrict__ mpb,
                                                     float* __restrict__ xs,
                                                     u16* __restrict__ msb)
{
  __shared__ float t[32][33];
  int task = blockIdx.z >> 2;
  int b = blockIdx.z & 3;
  const float* src = task ? memp : x;
  const float* w8 = task ? mpw : ipw;
  float acc = task ? mpb[0] : ipb[0];
  int h = blockIdx.y * 32 + threadIdx.y;
  int w = blockIdx.x * 32 + threadIdx.x;
#pragma unroll
  for (int c = 0; c < 8; ++c)
    acc += src[(((size_t)b * 8 + c) * 1024 + h) * 1024 + w] * w8[c];
  t[threadIdx.y][threadIdx.x] = acc;
  __syncthreads();
  int wo = blockIdx.x * 32 + threadIdx.y;
  int ho = blockIdx.y * 32 + threadIdx.x;
  float v = t[threadIdx.x][threadIdx.y];
  size_t o = ((size_t)b * 1024 + wo) * 1024 + ho;
  if (task) msb[o] = f2bf(v);
  else xs[o] = v;
}

// LayerNorm over 1024, f32 in -> bf16 out. one block per row.
__global__ __launch_bounds__(256) void ln_kernel(const float* __restrict__ x,
                                                 const float* __restrict__ g,
                                                 const float* __restrict__ b,
                                                 u16* __restrict__ out)
{
  int row = blockIdx.x, tid = threadIdx.x;
  float4 v = ((const float4*)(x + (size_t)row * 1024))[tid];
  float s = v.x + v.y + v.z + v.w;
  float s2 = v.x * v.x + v.y * v.y + v.z * v.z + v.w * v.w;
#pragma unroll
  for (int o = 32; o; o >>= 1) { s += __shfl_down(s, o); s2 += __shfl_down(s2, o); }
  __shared__ float rs[4], rs2[4];
  int wid = tid >> 6, lane = tid & 63;
  if (lane == 0) { rs[wid] = s; rs2[wid] = s2; }
  __syncthreads();
  s = rs[0] + rs[1] + rs[2] + rs[3];
  s2 = rs2[0] + rs2[1] + rs2[2] + rs2[3];
  float mean = s * (1.f / 1024.f);
  float var = s2 * (1.f / 1024.f) - mean * mean;
  float rstd = rsqrtf(var + 1e-5f);
  float4 gv = ((const float4*)g)[tid];
  float4 bv = ((const float4*)b)[tid];
  ushort4 o;
  o.x = f2bf((v.x - mean) * rstd * gv.x + bv.x);
  o.y = f2bf((v.y - mean) * rstd * gv.y + bv.y);
  o.z = f2bf((v.z - mean) * rstd * gv.z + bv.z);
  o.w = f2bf((v.w - mean) * rstd * gv.w + bv.w);
  ((ushort4*)out)[(size_t)row * 256 + tid] = o;
}

// depthwise conv k=3 pad=1 along t for Q (sel=0) and K (sel=1) from fused QKV buffer.
__global__ __launch_bounds__(128) void dwconv_qk_kernel(const u16* __restrict__ qkv,
                                                        const float* __restrict__ qc,
                                                        const float* __restrict__ kc,
                                                        u16* __restrict__ Qc,
                                                        u16* __restrict__ Kc)
{
  int sel = blockIdx.y;
  int row = blockIdx.x;     // b*1024 + t
  int t = row & 1023;
  int c0 = threadIdx.x * 8;
  const u16* r0 = qkv + (size_t)row * 3072 + (sel << 10) + c0;
  const float* wc = sel ? kc : qc;
  u16* dst = (sel ? Kc : Qc) + (size_t)row * 1024 + c0;
  u16x8 zv = {0, 0, 0, 0, 0, 0, 0, 0};
  u16x8 xm = zv, xp = zv;
  if (t > 0) xm = *(const u16x8*)(r0 - 3072);
  u16x8 xc = *(const u16x8*)r0;
  if (t < 1023) xp = *(const u16x8*)(r0 + 3072);
  u16x8 o;
#pragma unroll
  for (int j = 0; j < 8; ++j) {
    int c = c0 + j;
    float v = bf2f(xm[j]) * wc[c * 3 + 0] + bf2f(xc[j]) * wc[c * 3 + 1] + bf2f(xp[j]) * wc[c * 3 + 2];
    o[j] = f2bf(v);
  }
  *(u16x8*)dst = o;
}

// depthwise conv + transposed store for V: out[(b*4+c/256)][c%256][t] from qkv col 2048+c
__global__ __launch_bounds__(1024) void dwconv_t_kernel(const u16* __restrict__ qkv,
                                                        const float* __restrict__ wc,
                                                        u16* __restrict__ out)
{
  __shared__ float tile[32][33];
  int b = blockIdx.z;
  int t = blockIdx.x * 32 + threadIdx.y;
  int c = blockIdx.y * 32 + threadIdx.x;
  size_t base = ((size_t)b * 1024 + t) * 3072 + 2048 + c;
  float xm = (t > 0) ? bf2f(qkv[base - 3072]) : 0.f;
  float xc = bf2f(qkv[base]);
  float xp = (t < 1023) ? bf2f(qkv[base + 3072]) : 0.f;
  tile[threadIdx.y][threadIdx.x] = xm * wc[c * 3 + 0] + xc * wc[c * 3 + 1] + xp * wc[c * 3 + 2];
  __syncthreads();
  int c2 = blockIdx.y * 32 + threadIdx.y;
  int t2 = blockIdx.x * 32 + threadIdx.x;
  int z = b * 4 + (c2 >> 8);
  out[((size_t)z * 256 + (c2 & 255)) * 1024 + t2] = f2bf(tile[threadIdx.x][threadIdx.y]);
}

// row softmax over 1024, f32 in -> bf16 out
__global__ __launch_bounds__(256) void softmax_kernel(const float* __restrict__ qk,
                                                      u16* __restrict__ P)
{
  size_t row = blockIdx.x;
  int tid = threadIdx.x;
  float4 v = ((const float4*)(qk + row * 1024))[tid];
  float m = fmaxf(fmaxf(v.x, v.y), fmaxf(v.z, v.w));
#pragma unroll
  for (int o = 32; o; o >>= 1) m = fmaxf(m, __shfl_down(m, o));
  __shared__ float red[4];
  int wid = tid >> 6, lane = tid & 63;
  if (lane == 0) red[wid] = m;
  __syncthreads();
  m = fmaxf(fmaxf(red[0], red[1]), fmaxf(red[2], red[3]));
  float e0 = __expf(v.x - m), e1 = __expf(v.y - m), e2 = __expf(v.z - m), e3 = __expf(v.w - m);
  float s = e0 + e1 + e2 + e3;
#pragma unroll
  for (int o = 32; o; o >>= 1) s += __shfl_down(s, o);
  __syncthreads();
  if (lane == 0) red[wid] = s;
  __syncthreads();
  s = red[0] + red[1] + red[2] + red[3];
  float rinv = 1.f / s;
  ushort4 o;
  o.x = f2bf(e0 * rinv); o.y = f2bf(e1 * rinv); o.z = f2bf(e2 * rinv); o.w = f2bf(e3 * rinv);
  ((ushort4*)P)[row * 256 + tid] = o;
}

// 12 fused f32->bf16 casts of 1M elements each (weight prep, one launch)
struct CastJobs { const float* s[12]; u16* d[12]; };
__global__ __launch_bounds__(256) void cast12_kernel(CastJobs J)
{
  int j = blockIdx.y;
  int i = blockIdx.x * 256 + threadIdx.x;   // 262144 float4 per job
  float4 v = ((const float4*)J.s[j])[i];
  ushort4 o;
  o.x = f2bf(v.x); o.y = f2bf(v.y); o.z = f2bf(v.z); o.w = f2bf(v.w);
  ((ushort4*)J.d[j])[i] = o;
}

// pw [256][1024] f32 -> pwT [1024][256] bf16
__global__ __launch_bounds__(1024) void pwt_kernel(const float* __restrict__ pw,
                                                   u16* __restrict__ pwT)
{
  __shared__ float tile[32][33];
  int d = blockIdx.y * 32 + threadIdx.y;
  int t = blockIdx.x * 32 + threadIdx.x;
  tile[threadIdx.y][threadIdx.x] = pw[(size_t)d * 1024 + t];
  __syncthreads();
  int t2 = blockIdx.x * 32 + threadIdx.y;
  int d2 = blockIdx.y * 32 + threadIdx.x;
  pwT[(size_t)t2 * 256 + d2] = f2bf(tile[threadIdx.x][threadIdx.y]);
}

// out[b][h][w] = xs[b][w][h], f32
__global__ __launch_bounds__(1024) void tout_kernel(const float* __restrict__ xs,
                                                    float* __restrict__ out)
{
  __shared__ float tile[32][33];
  int b = blockIdx.z;
  int w = blockIdx.x * 32 + threadIdx.y;
  int h = blockIdx.y * 32 + threadIdx.x;
  tile[threadIdx.y][threadIdx.x] = xs[((size_t)b * 1024 + w) * 1024 + h];
  __syncthreads();
  int h2 = blockIdx.y * 32 + threadIdx.y;
  int w2 = blockIdx.x * 32 + threadIdx.x;
  out[((size_t)b * 1024 + h2) * 1024 + w2] = tile[threadIdx.x][threadIdx.y];
}

static void run_attn(hipStream_t stream, float* xs, const u16* qsrc, const u16* kvsrc, int asplit,
                     u16* QKVraw, u16* Qc, u16* Kc, u16* Vt, u16* P, u16* Am,
                     const u16* wqkv, const u16* wo, const u16* pwt,
                     const float* qc, const float* kc, const float* vc,
                     const float* prevqk, float* qko)
{
  dim3 blk(512);
  // fused QKV projection: M=4096, N=3072, K=1024. A per-column-block select.
  gemm256<EPI_BF16, false><<<dim3(12, 32, 1), blk, 0, stream>>>(
      qsrc, kvsrc, asplit, 0, 0, 1024, nullptr, 0,
      wqkv, 0, 0, 1024, nullptr, 0, 0, 0,
      1024, 0, QKVraw, 0, 0, 3072, nullptr, 0, 0, 1.f);
  dwconv_qk_kernel<<<dim3(4096, 2), 128, 0, stream>>>(QKVraw, qc, kc, Qc, Kc);
  dwconv_t_kernel<<<dim3(32, 32, 4), dim3(32, 32), 0, stream>>>(QKVraw, vc, Vt);
  // qk = (Q Kt + pwT Qt)/32 + prev, K=512 split at 256. 16 batches (b,n).
  gemm256<EPI_QK, true><<<dim3(4, 8, 16), blk, 0, stream>>>(
      Qc, Qc, 1 << 30, 1048576, 256, 1024, pwt, 256,
      Kc, 1048576, 256, 1024, Qc, 1048576, 256, 1024,
      512, 256, qko, 4194304, 1048576, 1024, prevqk, 1048576, 1024, 0.03125f);
  softmax_kernel<<<16384, 256, 0, stream>>>(qko, P);
  // PV: per z, [1024x1024]x[1024x256]
  gemm256<EPI_BF16, false><<<dim3(1, 8, 16), blk, 0, stream>>>(
      P, P, 1 << 30, 4194304, 1048576, 1024, nullptr, 0,
      Vt, 1048576, 262144, 1024, nullptr, 0, 0, 0,
      1024, 0, Am, 1048576, 256, 1024, nullptr, 0, 0, 1.f);
  // O-proj + residual add into xs (f32)
  gemm256<EPI_ADDF32, false><<<dim3(4, 32, 1), blk, 0, stream>>>(
      Am, Am, 1 << 30, 0, 0, 1024, nullptr, 0,
      wo, 0, 0, 1024, nullptr, 0, 0, 0,
      1024, 0, xs, 0, 0, 1024, nullptr, 0, 0, 1.f);
}

extern "C" void kernel_launch(void* const* d_in, const int* in_sizes, int n_in,
                              void* d_out, int out_size, void* d_ws, size_t ws_size,
                              hipStream_t stream)
{
  (void)in_sizes; (void)n_in; (void)out_size; (void)ws_size;
  const float* x    = (const float*)d_in[0];
  const float* memp = (const float*)d_in[1];
  const float* pqk1 = (const float*)d_in[2];
  const float* pqk2 = (const float*)d_in[3];
  const float* ip_w = (const float*)d_in[4];
  const float* ip_b = (const float*)d_in[5];
  const float* mp_w = (const float*)d_in[6];
  const float* mp_b = (const float*)d_in[7];
  const float* ln1g = (const float*)d_in[8];
  const float* ln1b = (const float*)d_in[9];
  const float* ln2g = (const float*)d_in[10];
  const float* ln2b = (const float*)d_in[11];
  const float* ln3g = (const float*)d_in[12];
  const float* ln3b = (const float*)d_in[13];
  const float* a1qw = (const float*)d_in[14];
  const float* a1qc = (const float*)d_in[15];
  const float* a1kw = (const float*)d_in[16];
  const float* a1kc = (const float*)d_in[17];
  const float* a1vw = (const float*)d_in[18];
  const float* a1vc = (const float*)d_in[19];
  const float* a1ow = (const float*)d_in[20];
  const float* a1pw = (const float*)d_in[21];
  const float* a2qw = (const float*)d_in[22];
  const float* a2qc = (const float*)d_in[23];
  const float* a2kw = (const float*)d_in[24];
  const float* a2kc = (const float*)d_in[25];
  const float* a2vw = (const float*)d_in[26];
  const float* a2vc = (const float*)d_in[27];
  const float* a2ow = (const float*)d_in[28];
  const float* a2pw = (const float*)d_in[29];
  const float* l1w  = (const float*)d_in[30];
  const float* l2w  = (const float*)d_in[31];

  float* outp = (float*)d_out;
  float* qk1o = outp + 4194304;    // [4][4][1024][1024]
  float* qk2o = outp + 20971520;

  const size_t MB = 1024 * 1024;
  char* W = (char*)d_ws;
  float* xs   = (float*)(W);             // 16MB f32 [4][1024w][1024h]
  u16* msb    = (u16*)(W + 16 * MB);     // 8MB bf16
  u16* xln    = (u16*)(W + 24 * MB);     // 8MB
  u16* QKVraw = (u16*)(W + 32 * MB);     // 24MB [4096][3072]
  u16* Qc     = (u16*)(W + 56 * MB);     // 8MB
  u16* Kc     = (u16*)(W + 64 * MB);     // 8MB
  u16* Vt     = (u16*)(W + 72 * MB);     // 8MB  [16][256][1024]
  u16* P      = (u16*)(W + 80 * MB);     // 32MB [16][1024][1024]
  u16* Am     = (u16*)(W + 112 * MB);    // 8MB
  u16* wqkv1  = (u16*)(W + 120 * MB);    // 6MB [3072][1024]
  u16* wqkv2  = (u16*)(W + 126 * MB);    // 6MB
  u16* wo1    = (u16*)(W + 132 * MB);    // 2MB
  u16* wo2    = (u16*)(W + 134 * MB);    // 2MB
  u16* wl1    = (u16*)(W + 136 * MB);    // 4MB [2048][1024]
  u16* wl2    = (u16*)(W + 140 * MB);    // 4MB [1024][2048]
  u16* pwt1   = (u16*)(W + 144 * MB);    // 0.5MB [1024][256]
  u16* pwt2   = (u16*)(W + 144 * MB + 512 * 1024);
  u16* H1     = QKVraw;                  // 16MB overlay (dead in FFN)

  // weight prep: one fused cast launch + 2 pw transposes
  CastJobs J;
  J.s[0] = a1qw; J.d[0] = wqkv1;
  J.s[1] = a1kw; J.d[1] = wqkv1 + 1048576;
  J.s[2] = a1vw; J.d[2] = wqkv1 + 2097152;
  J.s[3] = a2qw; J.d[3] = wqkv2;
  J.s[4] = a2kw; J.d[4] = wqkv2 + 1048576;
  J.s[5] = a2vw; J.d[5] = wqkv2 + 2097152;
  J.s[6] = a1ow; J.d[6] = wo1;
  J.s[7] = a2ow; J.d[7] = wo2;
  J.s[8] = l1w;            J.d[8] = wl1;
  J.s[9] = l1w + 1048576;  J.d[9] = wl1 + 1048576;
  J.s[10] = l2w;           J.d[10] = wl2;
  J.s[11] = l2w + 1048576; J.d[11] = wl2 + 1048576;
  cast12_kernel<<<dim3(1024, 12), 256, 0, stream>>>(J);
  pwt_kernel<<<dim3(32, 8, 1), dim3(32, 32), 0, stream>>>(a1pw, pwt1);
  pwt_kernel<<<dim3(32, 8, 1), dim3(32, 32), 0, stream>>>(a2pw, pwt2);

  // input projections (fused: x->xs f32 and mem->msb bf16)
  proj2_kernel<<<dim3(32, 32, 8), dim3(32, 32), 0, stream>>>(
      x, memp, ip_w, ip_b, mp_w, mp_b, xs, msb);

  // attention 1 (self): q and kv both from LN1(xs)
  ln_kernel<<<4096, 256, 0, stream>>>(xs, ln1g, ln1b, xln);
  run_attn(stream, xs, xln, xln, 1 << 30, QKVraw, Qc, Kc, Vt, P, Am,
           wqkv1, wo1, pwt1, a1qc, a1kc, a1vc, pqk1, qk1o);

  // attention 2 (cross): q from LN2(xs), kv from ms
  ln_kernel<<<4096, 256, 0, stream>>>(xs, ln2g, ln2b, xln);
  run_attn(stream, xs, xln, msb, 1024, QKVraw, Qc, Kc, Vt, P, Am,
           wqkv2, wo2, pwt2, a2qc, a2kc, a2vc, pqk2, qk2o);

  // FFN
  ln_kernel<<<4096, 256, 0, stream>>>(xs, ln3g, ln3b, xln);
  gemm256<EPI_RELU2, false><<<dim3(8, 32, 1), dim3(512), 0, stream>>>(
      xln, xln, 1 << 30, 0, 0, 1024, nullptr, 0,
      wl1, 0, 0, 1024, nullptr, 0, 0, 0,
      1024, 0, H1, 0, 0, 2048, nullptr, 0, 0, 1.f);
  gemm256<EPI_ADDF32, false><<<dim3(4, 32, 1), dim3(512), 0, stream>>>(
      H1, H1, 1 << 30, 0, 0, 2048, nullptr, 0,
      wl2, 0, 0, 2048, nullptr, 0, 0, 0,
      2048, 0, xs, 0, 0, 1024, nullptr, 0, 0, 1.f);

  // final transpose to out[b][1][bins][w]
  tout_kernel<<<dim3(32, 32, 4), dim3(32, 32), 0, stream>>>(xs, outp);
}

// Round 4
// 517.944 us; speedup vs baseline: 1.3844x; 1.1195x over previous
//
#include <hip/hip_runtime.h>
#include <stdint.h>

typedef unsigned short u16;
typedef __bf16 bfv8 __attribute__((ext_vector_type(8)));
typedef float f32x4 __attribute__((ext_vector_type(4)));
typedef unsigned short u16x8 __attribute__((ext_vector_type(8)));

#define DI __device__ __forceinline__

DI u16 f2bf(float f) {
  union { float f; unsigned u; } c; c.f = f;
  unsigned r = c.u + 0x7FFFu + ((c.u >> 16) & 1u);
  return (u16)(r >> 16);
}
DI float bf2f(u16 b) {
  union { unsigned u; float f; } c; c.u = ((unsigned)b) << 16;
  return c.f;
}

enum { EPI_BF16 = 0, EPI_RELU2 = 1, EPI_ADDF32 = 2, EPI_QK = 3 };

#define GLDS(g, l)                                                              \
  __builtin_amdgcn_global_load_lds((const __attribute__((address_space(1))) void*)(g), \
                                   (__attribute__((address_space(3))) void*)(l), 16, 0, 0)

#define VMCNT_BAR(N)                                        \
  do {                                                      \
    asm volatile("s_waitcnt vmcnt(" #N ")" ::: "memory");   \
    __builtin_amdgcn_sched_barrier(0);                      \
    __builtin_amdgcn_s_barrier();                           \
    __builtin_amdgcn_sched_barrier(0);                      \
  } while (0)

// C[m,n] = sum_k A[m,k]*B[n,k]. Tile 128xBN (BN=128|256), BK=64, 512 thr
// (8 waves, 2Mx4N), 3-stage LDS pipeline with counted vmcnt + setprio.
// A source selectable per output-column block (n0>=asplit -> Akv) for fused QKV.
// KSPLIT: k>=ksp reads A2 (unbatched)/B2 (batched).
// LDS XOR swizzle: phys chunk (row,c) holds global chunk (row, c^(row&7)).
template <int EPI, bool KSPLIT, int BN>
__global__ __launch_bounds__(512) void gemm256(
    const u16* __restrict__ Aq, const u16* __restrict__ Akv, int asplit,
    long a1q, long a1r, int lda1,
    const u16* __restrict__ A2, int lda2,
    const u16* __restrict__ B1, long b1q, long b1r, int ldb1,
    const u16* __restrict__ B2, long b2q, long b2r, int ldb2,
    int K, int ksp,
    void* __restrict__ Cv, long cq, long cr, int ldc,
    const float* __restrict__ extra, long eq, int lde,
    float scale)
{
  constexpr int NJ = BN / 64;            // output frags per wave in n
  constexpr int NBL = BN / 64;           // B staging loads per tile
  constexpr int SS = 8192 + BN * 64;     // u16 per stage
  constexpr int LPS = 2 + NBL;           // global_load_lds per stage
  __shared__ __align__(16) u16 lds[3 * SS];
  const int tid = threadIdx.x;
  const int wid = tid >> 6, lane = tid & 63;
  const long zq = blockIdx.z >> 2, zr = blockIdx.z & 3;
  const int m0 = blockIdx.y * 128, n0 = blockIdx.x * BN;
  const u16* Ab = ((n0 >= asplit) ? Akv : Aq) + zq * a1q + zr * a1r;
  const u16* Bb = B1 + zq * b1q + zr * b1r;
  const u16* B2b = KSPLIT ? (B2 + zq * b2q + zr * b2r) : (const u16*)nullptr;
  const int wm = (wid >> 2) * 64, wn = (wid & 3) * (BN / 4);
  const int fr = lane & 15, fq = lane >> 4;

  f32x4 acc[4][NJ];
#pragma unroll
  for (int i = 0; i < 4; ++i)
#pragma unroll
    for (int j = 0; j < NJ; ++j)
      acc[i][j] = (f32x4){0.f, 0.f, 0.f, 0.f};

  const int nt = K >> 6;

  auto STAGE = [&](int tt, int sb) {
    const int k0 = tt << 6;
    u16* Ld = &lds[sb * SS];
    const u16* Asrc; int la; const u16* Bsrc; int lb;
    if (!KSPLIT || k0 < ksp) { Asrc = Ab + k0; la = lda1; Bsrc = Bb + k0; lb = ldb1; }
    else { Asrc = A2 + (k0 - ksp); la = lda2; Bsrc = B2b + (k0 - ksp); lb = ldb2; }
#pragma unroll
    for (int l = 0; l < 2; ++l) {               // A: 1024 chunks / 512 thr
      int idx = (l << 9) + tid;
      int row = idx >> 3;
      int sc = ((idx & 7) ^ (row & 7)) << 3;    // pre-swizzled global column
      GLDS(Asrc + (size_t)(m0 + row) * la + sc,
           Ld + (((l << 3) + wid) << 9));
    }
#pragma unroll
    for (int l = 0; l < NBL; ++l) {             // B: BN*8 chunks / 512 thr
      int idx = (l << 9) + tid;
      int row = idx >> 3;
      int sc = ((idx & 7) ^ (row & 7)) << 3;
      GLDS(Bsrc + (size_t)(n0 + row) * lb + sc,
           Ld + 8192 + (((l << 3) + wid) << 9));
    }
  };

  auto COMPUTE = [&](int cb) {
    const u16* As = &lds[cb * SS];
    const u16* Bs = As + 8192;
#pragma unroll
    for (int ks = 0; ks < 2; ++ks) {
      bfv8 av[4];
#pragma unroll
      for (int i = 0; i < 4; ++i) {
        int ra = wm + i * 16 + fr;
        int ca = (((ks << 2) + fq) ^ (ra & 7)) << 3;
        av[i] = *(const bfv8*)&As[(ra << 6) + ca];
      }
#pragma unroll
      for (int nh = 0; nh < NJ / 2; ++nh) {
        bfv8 bv[2];
#pragma unroll
        for (int j = 0; j < 2; ++j) {
          int rb = wn + (nh << 5) + (j << 4) + fr;
          int cb2 = (((ks << 2) + fq) ^ (rb & 7)) << 3;
          bv[j] = *(const bfv8*)&Bs[(rb << 6) + cb2];
        }
        __builtin_amdgcn_s_setprio(1);
#pragma unroll
        for (int i = 0; i < 4; ++i) {
          acc[i][(nh << 1)] = __builtin_amdgcn_mfma_f32_16x16x32_bf16(av[i], bv[0], acc[i][(nh << 1)], 0, 0, 0);
          acc[i][(nh << 1) + 1] = __builtin_amdgcn_mfma_f32_16x16x32_bf16(av[i], bv[1], acc[i][(nh << 1) + 1], 0, 0, 0);
        }
        __builtin_amdgcn_s_setprio(0);
      }
    }
  };

  STAGE(0, 0);
  STAGE(1, 1);
  if constexpr (LPS == 6) VMCNT_BAR(6); else VMCNT_BAR(4);
  int cur = 0;
  for (int t = 0; t < nt; ++t) {
    if (t + 2 < nt) {
      int stg = cur + 2; if (stg >= 3) stg -= 3;
      STAGE(t + 2, stg);        // issue t+2 before computing t
      COMPUTE(cur);
      if constexpr (LPS == 6) VMCNT_BAR(6); else VMCNT_BAR(4);
    } else if (t + 1 < nt) {
      COMPUTE(cur);
      VMCNT_BAR(0);
    } else {
      COMPUTE(cur);
    }
    cur = (cur == 2) ? 0 : cur + 1;
  }

  if constexpr (EPI == EPI_BF16 || EPI == EPI_RELU2) {
    u16* Cb = (u16*)Cv + zq * cq + zr * cr;
#pragma unroll
    for (int i = 0; i < 4; ++i)
#pragma unroll
      for (int j = 0; j < NJ; ++j)
#pragma unroll
        for (int r = 0; r < 4; ++r) {
          int row = m0 + wm + i * 16 + (fq << 2) + r;
          int col = n0 + wn + j * 16 + fr;
          float v = acc[i][j][r];
          if constexpr (EPI == EPI_RELU2) { v = fmaxf(v, 0.f); v = v * v; }
          Cb[(size_t)row * ldc + col] = f2bf(v);
        }
  } else if constexpr (EPI == EPI_ADDF32) {
    float* Cb = (float*)Cv + zq * cq + zr * cr;
#pragma unroll
    for (int i = 0; i < 4; ++i)
#pragma unroll
      for (int j = 0; j < NJ; ++j)
#pragma unroll
        for (int r = 0; r < 4; ++r) {
          int row = m0 + wm + i * 16 + (fq << 2) + r;
          int col = n0 + wn + j * 16 + fr;
          Cb[(size_t)row * ldc + col] += acc[i][j][r];
        }
  } else {  // EPI_QK
    float* Cb = (float*)Cv + zq * cq + zr * cr;
    const float* Eb = extra + (size_t)blockIdx.z * eq;
#pragma unroll
    for (int i = 0; i < 4; ++i)
#pragma unroll
      for (int j = 0; j < NJ; ++j)
#pragma unroll
        for (int r = 0; r < 4; ++r) {
          int row = m0 + wm + i * 16 + (fq << 2) + r;
          int col = n0 + wn + j * 16 + fr;
          Cb[(size_t)row * ldc + col] = acc[i][j][r] * scale + Eb[(size_t)row * lde + col];
        }
  }
}

// fused input projection, float4 both sides. z = b + 4*task.
// task0: x -> xs (f32, [b,w,h]). task1: mem -> msb (bf16, [b,w,h]).
// 64x64 (h,w) tile per block, 256 threads.
__global__ __launch_bounds__(256) void proj2v_kernel(const float* __restrict__ x,
                                                     const float* __restrict__ memp,
                                                     const float* __restrict__ ipw,
                                                     const float* __restrict__ ipb,
                                                     const float* __restrict__ mpw,
                                                     const float* __restrict__ mpb,
                                                     float* __restrict__ xs,
                                                     u16* __restrict__ msb)
{
  __shared__ float lt[64][65];   // [w][h]
  int task = blockIdx.z >> 2;
  int b = blockIdx.z & 3;
  const float* src = task ? memp : x;
  const float* w8 = task ? mpw : ipw;
  float bias = task ? mpb[0] : ipb[0];
  int h0 = blockIdx.y * 64, w0 = blockIdx.x * 64;
  int tx = threadIdx.x & 15;         // float4 index along w
  int hy = threadIdx.x >> 4;         // h row (16 rows per pass)
#pragma unroll
  for (int p = 0; p < 4; ++p) {
    int h = h0 + hy + p * 16;
    f32x4 acc = {bias, bias, bias, bias};
#pragma unroll
    for (int c = 0; c < 8; ++c) {
      f32x4 v = *(const f32x4*)&src[(((size_t)b * 8 + c) * 1024 + h) * 1024 + w0 + tx * 4];
      float wc = w8[c];
      acc.x += v.x * wc; acc.y += v.y * wc; acc.z += v.z * wc; acc.w += v.w * wc;
    }
    int hl = hy + p * 16;
    lt[tx * 4 + 0][hl] = acc.x;
    lt[tx * 4 + 1][hl] = acc.y;
    lt[tx * 4 + 2][hl] = acc.z;
    lt[tx * 4 + 3][hl] = acc.w;
  }
  __syncthreads();
  int hx = threadIdx.x & 15;         // float4 index along h
  int wy = threadIdx.x >> 4;         // w row
#pragma unroll
  for (int p = 0; p < 4; ++p) {
    int wl = wy + p * 16;
    f32x4 v;
    v.x = lt[wl][hx * 4 + 0];
    v.y = lt[wl][hx * 4 + 1];
    v.z = lt[wl][hx * 4 + 2];
    v.w = lt[wl][hx * 4 + 3];
    size_t o = ((size_t)b * 1024 + w0 + wl) * 1024 + h0 + hx * 4;
    if (task) {
      ushort4 ov;
      ov.x = f2bf(v.x); ov.y = f2bf(v.y); ov.z = f2bf(v.z); ov.w = f2bf(v.w);
      *(ushort4*)&msb[o] = ov;
    } else {
      *(f32x4*)&xs[o] = v;
    }
  }
}

// LayerNorm over 1024, f32 in -> bf16 out. one block per row.
__global__ __launch_bounds__(256) void ln_kernel(const float* __restrict__ x,
                                                 const float* __restrict__ g,
                                                 const float* __restrict__ b,
                                                 u16* __restrict__ out)
{
  int row = blockIdx.x, tid = threadIdx.x;
  float4 v = ((const float4*)(x + (size_t)row * 1024))[tid];
  float s = v.x + v.y + v.z + v.w;
  float s2 = v.x * v.x + v.y * v.y + v.z * v.z + v.w * v.w;
#pragma unroll
  for (int o = 32; o; o >>= 1) { s += __shfl_down(s, o); s2 += __shfl_down(s2, o); }
  __shared__ float rs[4], rs2[4];
  int wid = tid >> 6, lane = tid & 63;
  if (lane == 0) { rs[wid] = s; rs2[wid] = s2; }
  __syncthreads();
  s = rs[0] + rs[1] + rs[2] + rs[3];
  s2 = rs2[0] + rs2[1] + rs2[2] + rs2[3];
  float mean = s * (1.f / 1024.f);
  float var = s2 * (1.f / 1024.f) - mean * mean;
  float rstd = rsqrtf(var + 1e-5f);
  float4 gv = ((const float4*)g)[tid];
  float4 bv = ((const float4*)b)[tid];
  ushort4 o;
  o.x = f2bf((v.x - mean) * rstd * gv.x + bv.x);
  o.y = f2bf((v.y - mean) * rstd * gv.y + bv.y);
  o.z = f2bf((v.z - mean) * rstd * gv.z + bv.z);
  o.w = f2bf((v.w - mean) * rstd * gv.w + bv.w);
  ((ushort4*)out)[(size_t)row * 256 + tid] = o;
}

// depthwise conv k=3 pad=1 along t for Q (sel=0) and K (sel=1) from fused QKV buffer.
__global__ __launch_bounds__(128) void dwconv_qk_kernel(const u16* __restrict__ qkv,
                                                        const float* __restrict__ qc,
                                                        const float* __restrict__ kc,
                                                        u16* __restrict__ Qc,
                                                        u16* __restrict__ Kc)
{
  int sel = blockIdx.y;
  int row = blockIdx.x;     // b*1024 + t
  int t = row & 1023;
  int c0 = threadIdx.x * 8;
  const u16* r0 = qkv + (size_t)row * 3072 + (sel << 10) + c0;
  const float* wc = sel ? kc : qc;
  u16* dst = (sel ? Kc : Qc) + (size_t)row * 1024 + c0;
  u16x8 zv = {0, 0, 0, 0, 0, 0, 0, 0};
  u16x8 xm = zv, xp = zv;
  if (t > 0) xm = *(const u16x8*)(r0 - 3072);
  u16x8 xc = *(const u16x8*)r0;
  if (t < 1023) xp = *(const u16x8*)(r0 + 3072);
  u16x8 o;
#pragma unroll
  for (int j = 0; j < 8; ++j) {
    int c = c0 + j;
    float v = bf2f(xm[j]) * wc[c * 3 + 0] + bf2f(xc[j]) * wc[c * 3 + 1] + bf2f(xp[j]) * wc[c * 3 + 2];
    o[j] = f2bf(v);
  }
  *(u16x8*)dst = o;
}

// depthwise conv + transposed store for V: out[(b*4+c/256)][c%256][t] from qkv col 2048+c
__global__ __launch_bounds__(1024) void dwconv_t_kernel(const u16* __restrict__ qkv,
                                                        const float* __restrict__ wc,
                                                        u16* __restrict__ out)
{
  __shared__ float tile[32][33];
  int b = blockIdx.z;
  int t = blockIdx.x * 32 + threadIdx.y;
  int c = blockIdx.y * 32 + threadIdx.x;
  size_t base = ((size_t)b * 1024 + t) * 3072 + 2048 + c;
  float xm = (t > 0) ? bf2f(qkv[base - 3072]) : 0.f;
  float xc = bf2f(qkv[base]);
  float xp = (t < 1023) ? bf2f(qkv[base + 3072]) : 0.f;
  tile[threadIdx.y][threadIdx.x] = xm * wc[c * 3 + 0] + xc * wc[c * 3 + 1] + xp * wc[c * 3 + 2];
  __syncthreads();
  int c2 = blockIdx.y * 32 + threadIdx.y;
  int t2 = blockIdx.x * 32 + threadIdx.x;
  int z = b * 4 + (c2 >> 8);
  out[((size_t)z * 256 + (c2 & 255)) * 1024 + t2] = f2bf(tile[threadIdx.x][threadIdx.y]);
}

// row softmax over 1024, f32 in -> bf16 out
__global__ __launch_bounds__(256) void softmax_kernel(const float* __restrict__ qk,
                                                      u16* __restrict__ P)
{
  size_t row = blockIdx.x;
  int tid = threadIdx.x;
  float4 v = ((const float4*)(qk + row * 1024))[tid];
  float m = fmaxf(fmaxf(v.x, v.y), fmaxf(v.z, v.w));
#pragma unroll
  for (int o = 32; o; o >>= 1) m = fmaxf(m, __shfl_down(m, o));
  __shared__ float red[4];
  int wid = tid >> 6, lane = tid & 63;
  if (lane == 0) red[wid] = m;
  __syncthreads();
  m = fmaxf(fmaxf(red[0], red[1]), fmaxf(red[2], red[3]));
  float e0 = __expf(v.x - m), e1 = __expf(v.y - m), e2 = __expf(v.z - m), e3 = __expf(v.w - m);
  float s = e0 + e1 + e2 + e3;
#pragma unroll
  for (int o = 32; o; o >>= 1) s += __shfl_down(s, o);
  __syncthreads();
  if (lane == 0) red[wid] = s;
  __syncthreads();
  s = red[0] + red[1] + red[2] + red[3];
  float rinv = 1.f / s;
  ushort4 o;
  o.x = f2bf(e0 * rinv); o.y = f2bf(e1 * rinv); o.z = f2bf(e2 * rinv); o.w = f2bf(e3 * rinv);
  ((ushort4*)P)[row * 256 + tid] = o;
}

// 12 fused f32->bf16 casts of 1M elements each (weight prep, one launch)
struct CastJobs { const float* s[12]; u16* d[12]; };
__global__ __launch_bounds__(256) void cast12_kernel(CastJobs J)
{
  int j = blockIdx.y;
  int i = blockIdx.x * 256 + threadIdx.x;   // 262144 float4 per job
  float4 v = ((const float4*)J.s[j])[i];
  ushort4 o;
  o.x = f2bf(v.x); o.y = f2bf(v.y); o.z = f2bf(v.z); o.w = f2bf(v.w);
  ((ushort4*)J.d[j])[i] = o;
}

// pw [256][1024] f32 -> pwT [1024][256] bf16
__global__ __launch_bounds__(1024) void pwt_kernel(const float* __restrict__ pw,
                                                   u16* __restrict__ pwT)
{
  __shared__ float tile[32][33];
  int d = blockIdx.y * 32 + threadIdx.y;
  int t = blockIdx.x * 32 + threadIdx.x;
  tile[threadIdx.y][threadIdx.x] = pw[(size_t)d * 1024 + t];
  __syncthreads();
  int t2 = blockIdx.x * 32 + threadIdx.y;
  int d2 = blockIdx.y * 32 + threadIdx.x;
  pwT[(size_t)t2 * 256 + d2] = f2bf(tile[threadIdx.x][threadIdx.y]);
}

// out[b][h][w] = xs[b][w][h], f32
__global__ __launch_bounds__(1024) void tout_kernel(const float* __restrict__ xs,
                                                    float* __restrict__ out)
{
  __shared__ float tile[32][33];
  int b = blockIdx.z;
  int w = blockIdx.x * 32 + threadIdx.y;
  int h = blockIdx.y * 32 + threadIdx.x;
  tile[threadIdx.y][threadIdx.x] = xs[((size_t)b * 1024 + w) * 1024 + h];
  __syncthreads();
  int h2 = blockIdx.y * 32 + threadIdx.y;
  int w2 = blockIdx.x * 32 + threadIdx.x;
  out[((size_t)b * 1024 + h2) * 1024 + w2] = tile[threadIdx.x][threadIdx.y];
}

static void run_attn(hipStream_t stream, float* xs, const u16* qsrc, const u16* kvsrc, int asplit,
                     u16* QKVraw, u16* Qc, u16* Kc, u16* Vt, u16* P, u16* Am,
                     const u16* wqkv, const u16* wo, const u16* pwt,
                     const float* qc, const float* kc, const float* vc,
                     const float* prevqk, float* qko)
{
  dim3 blk(512);
  // fused QKV projection: M=4096, N=3072, K=1024. A per-column-block select.
  gemm256<EPI_BF16, false, 256><<<dim3(12, 32, 1), blk, 0, stream>>>(
      qsrc, kvsrc, asplit, 0, 0, 1024, nullptr, 0,
      wqkv, 0, 0, 1024, nullptr, 0, 0, 0,
      1024, 0, QKVraw, 0, 0, 3072, nullptr, 0, 0, 1.f);
  dwconv_qk_kernel<<<dim3(4096, 2), 128, 0, stream>>>(QKVraw, qc, kc, Qc, Kc);
  dwconv_t_kernel<<<dim3(32, 32, 4), dim3(32, 32), 0, stream>>>(QKVraw, vc, Vt);
  // qk = (Q Kt + pwT Qt)/32 + prev, K=512 split at 256. 16 batches (b,n).
  gemm256<EPI_QK, true, 256><<<dim3(4, 8, 16), blk, 0, stream>>>(
      Qc, Qc, 1 << 30, 1048576, 256, 1024, pwt, 256,
      Kc, 1048576, 256, 1024, Qc, 1048576, 256, 1024,
      512, 256, qko, 4194304, 1048576, 1024, prevqk, 1048576, 1024, 0.03125f);
  softmax_kernel<<<16384, 256, 0, stream>>>(qko, P);
  // PV: per z, [1024x1024]x[1024x256] — BN=128 for full-machine grid (256 blocks)
  gemm256<EPI_BF16, false, 128><<<dim3(2, 8, 16), blk, 0, stream>>>(
      P, P, 1 << 30, 4194304, 1048576, 1024, nullptr, 0,
      Vt, 1048576, 262144, 1024, nullptr, 0, 0, 0,
      1024, 0, Am, 1048576, 256, 1024, nullptr, 0, 0, 1.f);
  // O-proj + residual add into xs (f32) — BN=128 (256 blocks)
  gemm256<EPI_ADDF32, false, 128><<<dim3(8, 32, 1), blk, 0, stream>>>(
      Am, Am, 1 << 30, 0, 0, 1024, nullptr, 0,
      wo, 0, 0, 1024, nullptr, 0, 0, 0,
      1024, 0, xs, 0, 0, 1024, nullptr, 0, 0, 1.f);
}

extern "C" void kernel_launch(void* const* d_in, const int* in_sizes, int n_in,
                              void* d_out, int out_size, void* d_ws, size_t ws_size,
                              hipStream_t stream)
{
  (void)in_sizes; (void)n_in; (void)out_size; (void)ws_size;
  const float* x    = (const float*)d_in[0];
  const float* memp = (const float*)d_in[1];
  const float* pqk1 = (const float*)d_in[2];
  const float* pqk2 = (const float*)d_in[3];
  const float* ip_w = (const float*)d_in[4];
  const float* ip_b = (const float*)d_in[5];
  const float* mp_w = (const float*)d_in[6];
  const float* mp_b = (const float*)d_in[7];
  const float* ln1g = (const float*)d_in[8];
  const float* ln1b = (const float*)d_in[9];
  const float* ln2g = (const float*)d_in[10];
  const float* ln2b = (const float*)d_in[11];
  const float* ln3g = (const float*)d_in[12];
  const float* ln3b = (const float*)d_in[13];
  const float* a1qw = (const float*)d_in[14];
  const float* a1qc = (const float*)d_in[15];
  const float* a1kw = (const float*)d_in[16];
  const float* a1kc = (const float*)d_in[17];
  const float* a1vw = (const float*)d_in[18];
  const float* a1vc = (const float*)d_in[19];
  const float* a1ow = (const float*)d_in[20];
  const float* a1pw = (const float*)d_in[21];
  const float* a2qw = (const float*)d_in[22];
  const float* a2qc = (const float*)d_in[23];
  const float* a2kw = (const float*)d_in[24];
  const float* a2kc = (const float*)d_in[25];
  const float* a2vw = (const float*)d_in[26];
  const float* a2vc = (const float*)d_in[27];
  const float* a2ow = (const float*)d_in[28];
  const float* a2pw = (const float*)d_in[29];
  const float* l1w  = (const float*)d_in[30];
  const float* l2w  = (const float*)d_in[31];

  float* outp = (float*)d_out;
  float* qk1o = outp + 4194304;    // [4][4][1024][1024]
  float* qk2o = outp + 20971520;

  const size_t MB = 1024 * 1024;
  char* W = (char*)d_ws;
  float* xs   = (float*)(W);             // 16MB f32 [4][1024w][1024h]
  u16* msb    = (u16*)(W + 16 * MB);     // 8MB bf16
  u16* xln    = (u16*)(W + 24 * MB);     // 8MB
  u16* QKVraw = (u16*)(W + 32 * MB);     // 24MB [4096][3072]
  u16* Qc     = (u16*)(W + 56 * MB);     // 8MB
  u16* Kc     = (u16*)(W + 64 * MB);     // 8MB
  u16* Vt     = (u16*)(W + 72 * MB);     // 8MB  [16][256][1024]
  u16* P      = (u16*)(W + 80 * MB);     // 32MB [16][1024][1024]
  u16* Am     = (u16*)(W + 112 * MB);    // 8MB
  u16* wqkv1  = (u16*)(W + 120 * MB);    // 6MB [3072][1024]
  u16* wqkv2  = (u16*)(W + 126 * MB);    // 6MB
  u16* wo1    = (u16*)(W + 132 * MB);    // 2MB
  u16* wo2    = (u16*)(W + 134 * MB);    // 2MB
  u16* wl1    = (u16*)(W + 136 * MB);    // 4MB [2048][1024]
  u16* wl2    = (u16*)(W + 140 * MB);    // 4MB [1024][2048]
  u16* pwt1   = (u16*)(W + 144 * MB);    // 0.5MB [1024][256]
  u16* pwt2   = (u16*)(W + 144 * MB + 512 * 1024);
  u16* H1     = QKVraw;                  // 16MB overlay (dead in FFN)

  // weight prep: one fused cast launch + 2 pw transposes
  CastJobs J;
  J.s[0] = a1qw; J.d[0] = wqkv1;
  J.s[1] = a1kw; J.d[1] = wqkv1 + 1048576;
  J.s[2] = a1vw; J.d[2] = wqkv1 + 2097152;
  J.s[3] = a2qw; J.d[3] = wqkv2;
  J.s[4] = a2kw; J.d[4] = wqkv2 + 1048576;
  J.s[5] = a2vw; J.d[5] = wqkv2 + 2097152;
  J.s[6] = a1ow; J.d[6] = wo1;
  J.s[7] = a2ow; J.d[7] = wo2;
  J.s[8] = l1w;            J.d[8] = wl1;
  J.s[9] = l1w + 1048576;  J.d[9] = wl1 + 1048576;
  J.s[10] = l2w;           J.d[10] = wl2;
  J.s[11] = l2w + 1048576; J.d[11] = wl2 + 1048576;
  cast12_kernel<<<dim3(1024, 12), 256, 0, stream>>>(J);
  pwt_kernel<<<dim3(32, 8, 1), dim3(32, 32), 0, stream>>>(a1pw, pwt1);
  pwt_kernel<<<dim3(32, 8, 1), dim3(32, 32), 0, stream>>>(a2pw, pwt2);

  // input projections (fused + float4 both sides)
  proj2v_kernel<<<dim3(16, 16, 8), 256, 0, stream>>>(
      x, memp, ip_w, ip_b, mp_w, mp_b, xs, msb);

  // attention 1 (self): q and kv both from LN1(xs)
  ln_kernel<<<4096, 256, 0, stream>>>(xs, ln1g, ln1b, xln);
  run_attn(stream, xs, xln, xln, 1 << 30, QKVraw, Qc, Kc, Vt, P, Am,
           wqkv1, wo1, pwt1, a1qc, a1kc, a1vc, pqk1, qk1o);

  // attention 2 (cross): q from LN2(xs), kv from ms
  ln_kernel<<<4096, 256, 0, stream>>>(xs, ln2g, ln2b, xln);
  run_attn(stream, xs, xln, msb, 1024, QKVraw, Qc, Kc, Vt, P, Am,
           wqkv2, wo2, pwt2, a2qc, a2kc, a2vc, pqk2, qk2o);

  // FFN
  ln_kernel<<<4096, 256, 0, stream>>>(xs, ln3g, ln3b, xln);
  gemm256<EPI_RELU2, false, 256><<<dim3(8, 32, 1), dim3(512), 0, stream>>>(
      xln, xln, 1 << 30, 0, 0, 1024, nullptr, 0,
      wl1, 0, 0, 1024, nullptr, 0, 0, 0,
      1024, 0, H1, 0, 0, 2048, nullptr, 0, 0, 1.f);
  gemm256<EPI_ADDF32, false, 128><<<dim3(8, 32, 1), dim3(512), 0, stream>>>(
      H1, H1, 1 << 30, 0, 0, 2048, nullptr, 0,
      wl2, 0, 0, 2048, nullptr, 0, 0, 0,
      2048, 0, xs, 0, 0, 1024, nullptr, 0, 0, 1.f);

  // final transpose to out[b][1][bins][w]
  tout_kernel<<<dim3(32, 32, 4), dim3(32, 32), 0, stream>>>(xs, outp);
}

// Round 5
// 515.279 us; speedup vs baseline: 1.3916x; 1.0052x over previous
//
#include <hip/hip_runtime.h>
#include <stdint.h>

typedef unsigned short u16;
typedef __bf16 bfv8 __attribute__((ext_vector_type(8)));
typedef float f32x4 __attribute__((ext_vector_type(4)));
typedef unsigned short u16x8 __attribute__((ext_vector_type(8)));

#define DI __device__ __forceinline__

DI u16 f2bf(float f) {
  union { float f; unsigned u; } c; c.f = f;
  unsigned r = c.u + 0x7FFFu + ((c.u >> 16) & 1u);
  return (u16)(r >> 16);
}
DI float bf2f(u16 b) {
  union { unsigned u; float f; } c; c.u = ((unsigned)b) << 16;
  return c.f;
}

enum { EPI_BF16 = 0, EPI_RELU2 = 1, EPI_ADDF32 = 2, EPI_QK = 3 };

#define GLDS(g, l)                                                              \
  __builtin_amdgcn_global_load_lds((const __attribute__((address_space(1))) void*)(g), \
                                   (__attribute__((address_space(3))) void*)(l), 16, 0, 0)

#define VMCNT_BAR(N)                                        \
  do {                                                      \
    asm volatile("s_waitcnt vmcnt(" #N ")" ::: "memory");   \
    __builtin_amdgcn_sched_barrier(0);                      \
    __builtin_amdgcn_s_barrier();                           \
    __builtin_amdgcn_sched_barrier(0);                      \
  } while (0)

// C[m,n] = sum_k A[m,k]*B[n,k]. Tile 128xBN (BN=128|256), BK=64, 512 thr
// (8 waves, 2Mx4N), 3-stage LDS pipeline with counted vmcnt + setprio.
// Bijective chunked XCD swizzle (m204): consecutive logical blocks cluster
// on one XCD for A/z-panel L2 reuse.
// A source selectable per output-column block (n0>=asplit -> Akv) for fused QKV.
// KSPLIT: k>=ksp reads A2 (unbatched)/B2 (batched).
// LDS XOR swizzle: phys chunk (row,c) holds global chunk (row, c^(row&7)).
template <int EPI, bool KSPLIT, int BN>
__global__ __launch_bounds__(512) void gemm256(
    const u16* __restrict__ Aq, const u16* __restrict__ Akv, int asplit,
    long a1q, long a1r, int lda1,
    const u16* __restrict__ A2, int lda2,
    const u16* __restrict__ B1, long b1q, long b1r, int ldb1,
    const u16* __restrict__ B2, long b2q, long b2r, int ldb2,
    int K, int ksp,
    void* __restrict__ Cv, long cq, long cr, int ldc,
    const float* __restrict__ extra, long eq, int lde,
    float scale)
{
  constexpr int NJ = BN / 64;
  constexpr int NBL = BN / 64;
  constexpr int SS = 8192 + BN * 64;
  constexpr int LPS = 2 + NBL;
  __shared__ __align__(16) u16 lds[3 * SS];
  const int tid = threadIdx.x;
  const int wid = tid >> 6, lane = tid & 63;

  // XCD chunked swizzle: dispatch-consecutive (round-robin over 8 XCDs) ->
  // logical-contiguous chunks per XCD.
  const int gx = gridDim.x, gy = gridDim.y;
  const int nwg = gx * gy * (int)gridDim.z;
  const int flat = blockIdx.x + gx * (blockIdx.y + gy * blockIdx.z);
  const int q = nwg >> 3, r = nwg & 7;
  const int xcd = flat & 7, idx = flat >> 3;
  const int wg = (xcd < r ? xcd * (q + 1) : r * (q + 1) + (xcd - r) * q) + idx;
  const int bx = wg % gx;
  const int tmp = wg / gx;
  const int by = tmp % gy;
  const int bz = tmp / gy;

  const long zq = bz >> 2, zr = bz & 3;
  const int m0 = by * 128, n0 = bx * BN;
  const u16* Ab = ((n0 >= asplit) ? Akv : Aq) + zq * a1q + zr * a1r;
  const u16* Bb = B1 + zq * b1q + zr * b1r;
  const u16* B2b = KSPLIT ? (B2 + zq * b2q + zr * b2r) : (const u16*)nullptr;
  const int wm = (wid >> 2) * 64, wn = (wid & 3) * (BN / 4);
  const int fr = lane & 15, fq = lane >> 4;

  f32x4 acc[4][NJ];
#pragma unroll
  for (int i = 0; i < 4; ++i)
#pragma unroll
    for (int j = 0; j < NJ; ++j)
      acc[i][j] = (f32x4){0.f, 0.f, 0.f, 0.f};

  const int nt = K >> 6;

  auto STAGE = [&](int tt, int sb) {
    const int k0 = tt << 6;
    u16* Ld = &lds[sb * SS];
    const u16* Asrc; int la; const u16* Bsrc; int lb;
    if (!KSPLIT || k0 < ksp) { Asrc = Ab + k0; la = lda1; Bsrc = Bb + k0; lb = ldb1; }
    else { Asrc = A2 + (k0 - ksp); la = lda2; Bsrc = B2b + (k0 - ksp); lb = ldb2; }
#pragma unroll
    for (int l = 0; l < 2; ++l) {               // A: 1024 chunks / 512 thr
      int idx2 = (l << 9) + tid;
      int row = idx2 >> 3;
      int sc = ((idx2 & 7) ^ (row & 7)) << 3;   // pre-swizzled global column
      GLDS(Asrc + (size_t)(m0 + row) * la + sc,
           Ld + (((l << 3) + wid) << 9));
    }
#pragma unroll
    for (int l = 0; l < NBL; ++l) {             // B: BN*8 chunks / 512 thr
      int idx2 = (l << 9) + tid;
      int row = idx2 >> 3;
      int sc = ((idx2 & 7) ^ (row & 7)) << 3;
      GLDS(Bsrc + (size_t)(n0 + row) * lb + sc,
           Ld + 8192 + (((l << 3) + wid) << 9));
    }
  };

  auto COMPUTE = [&](int cb) {
    const u16* As = &lds[cb * SS];
    const u16* Bs = As + 8192;
#pragma unroll
    for (int ks = 0; ks < 2; ++ks) {
      bfv8 av[4];
#pragma unroll
      for (int i = 0; i < 4; ++i) {
        int ra = wm + i * 16 + fr;
        int ca = (((ks << 2) + fq) ^ (ra & 7)) << 3;
        av[i] = *(const bfv8*)&As[(ra << 6) + ca];
      }
#pragma unroll
      for (int nh = 0; nh < NJ / 2; ++nh) {
        bfv8 bv[2];
#pragma unroll
        for (int j = 0; j < 2; ++j) {
          int rb = wn + (nh << 5) + (j << 4) + fr;
          int cb2 = (((ks << 2) + fq) ^ (rb & 7)) << 3;
          bv[j] = *(const bfv8*)&Bs[(rb << 6) + cb2];
        }
        __builtin_amdgcn_s_setprio(1);
#pragma unroll
        for (int i = 0; i < 4; ++i) {
          acc[i][(nh << 1)] = __builtin_amdgcn_mfma_f32_16x16x32_bf16(av[i], bv[0], acc[i][(nh << 1)], 0, 0, 0);
          acc[i][(nh << 1) + 1] = __builtin_amdgcn_mfma_f32_16x16x32_bf16(av[i], bv[1], acc[i][(nh << 1) + 1], 0, 0, 0);
        }
        __builtin_amdgcn_s_setprio(0);
      }
    }
  };

  STAGE(0, 0);
  STAGE(1, 1);
  if constexpr (LPS == 6) VMCNT_BAR(6); else VMCNT_BAR(4);
  int cur = 0;
  for (int t = 0; t < nt; ++t) {
    if (t + 2 < nt) {
      int stg = cur + 2; if (stg >= 3) stg -= 3;
      STAGE(t + 2, stg);        // issue t+2 before computing t
      COMPUTE(cur);
      if constexpr (LPS == 6) VMCNT_BAR(6); else VMCNT_BAR(4);
    } else if (t + 1 < nt) {
      COMPUTE(cur);
      VMCNT_BAR(0);
    } else {
      COMPUTE(cur);
    }
    cur = (cur == 2) ? 0 : cur + 1;
  }

  if constexpr (EPI == EPI_BF16 || EPI == EPI_RELU2) {
    u16* Cb = (u16*)Cv + zq * cq + zr * cr;
#pragma unroll
    for (int i = 0; i < 4; ++i)
#pragma unroll
      for (int j = 0; j < NJ; ++j)
#pragma unroll
        for (int r2 = 0; r2 < 4; ++r2) {
          int row = m0 + wm + i * 16 + (fq << 2) + r2;
          int col = n0 + wn + j * 16 + fr;
          float v = acc[i][j][r2];
          if constexpr (EPI == EPI_RELU2) { v = fmaxf(v, 0.f); v = v * v; }
          Cb[(size_t)row * ldc + col] = f2bf(v);
        }
  } else if constexpr (EPI == EPI_ADDF32) {
    float* Cb = (float*)Cv + zq * cq + zr * cr;
#pragma unroll
    for (int i = 0; i < 4; ++i)
#pragma unroll
      for (int j = 0; j < NJ; ++j)
#pragma unroll
        for (int r2 = 0; r2 < 4; ++r2) {
          int row = m0 + wm + i * 16 + (fq << 2) + r2;
          int col = n0 + wn + j * 16 + fr;
          Cb[(size_t)row * ldc + col] += acc[i][j][r2];
        }
  } else {  // EPI_QK
    float* Cb = (float*)Cv + zq * cq + zr * cr;
    const float* Eb = extra + (size_t)bz * eq;
#pragma unroll
    for (int i = 0; i < 4; ++i)
#pragma unroll
      for (int j = 0; j < NJ; ++j)
#pragma unroll
        for (int r2 = 0; r2 < 4; ++r2) {
          int row = m0 + wm + i * 16 + (fq << 2) + r2;
          int col = n0 + wn + j * 16 + fr;
          Cb[(size_t)row * ldc + col] = acc[i][j][r2] * scale + Eb[(size_t)row * lde + col];
        }
  }
}

// fused input projection, full-row contiguous reads.
// block: 1024 thr, owns (task, b, 16 h-rows) x all 1024 w; reads 8 channels.
// Wave load = 64 lanes x 16B = 1KB contiguous. Transpose via 64KB LDS,
// writes 64B (f32) / 32B (bf16) contiguous per lane along h.
__global__ __launch_bounds__(1024) void proj3_kernel(const float* __restrict__ x,
                                                     const float* __restrict__ memp,
                                                     const float* __restrict__ ipw,
                                                     const float* __restrict__ ipb,
                                                     const float* __restrict__ mpw,
                                                     const float* __restrict__ mpb,
                                                     float* __restrict__ xs,
                                                     u16* __restrict__ msb)
{
  __shared__ f32x4 lt[16][256];    // [h_local][w4]  64KB
  const int task = blockIdx.z;
  const int b = blockIdx.y;
  const int h0 = blockIdx.x * 16;
  const float* src = task ? memp : x;
  const float* w8 = task ? mpw : ipw;
  const float bias = task ? mpb[0] : ipb[0];
  const int t = threadIdx.x;
  const int w4 = t & 255, hl = t >> 8;
  float wr[8];
#pragma unroll
  for (int c = 0; c < 8; ++c) wr[c] = w8[c];
#pragma unroll
  for (int p = 0; p < 4; ++p) {
    const int hr = p * 4 + hl;
    const size_t rowbase = ((size_t)b * 8 * 1024 + (h0 + hr)) * 1024 + (w4 << 2);
    f32x4 acc = {bias, bias, bias, bias};
#pragma unroll
    for (int c = 0; c < 8; ++c) {
      f32x4 v = *(const f32x4*)&src[rowbase + (size_t)c * 1048576];
      acc.x += v.x * wr[c]; acc.y += v.y * wr[c]; acc.z += v.z * wr[c]; acc.w += v.w * wr[c];
    }
    lt[hr][w4] = acc;
  }
  __syncthreads();
  const int w = t;
  float o[16];
#pragma unroll
  for (int h = 0; h < 16; ++h)
    o[h] = ((const float*)&lt[h][0])[w];
  if (task) {
    u16* d = &msb[((size_t)b * 1024 + w) * 1024 + h0];
    u16x8 o0, o1;
#pragma unroll
    for (int h = 0; h < 8; ++h) { o0[h] = f2bf(o[h]); o1[h] = f2bf(o[h + 8]); }
    *(u16x8*)&d[0] = o0;
    *(u16x8*)&d[8] = o1;
  } else {
    float* d = &xs[((size_t)b * 1024 + w) * 1024 + h0];
#pragma unroll
    for (int p = 0; p < 4; ++p) {
      f32x4 v = {o[p * 4], o[p * 4 + 1], o[p * 4 + 2], o[p * 4 + 3]};
      *(f32x4*)&d[p * 4] = v;
    }
  }
}

// LayerNorm over 1024, f32 in -> bf16 out. one block per row.
__global__ __launch_bounds__(256) void ln_kernel(const float* __restrict__ x,
                                                 const float* __restrict__ g,
                                                 const float* __restrict__ b,
                                                 u16* __restrict__ out)
{
  int row = blockIdx.x, tid = threadIdx.x;
  float4 v = ((const float4*)(x + (size_t)row * 1024))[tid];
  float s = v.x + v.y + v.z + v.w;
  float s2 = v.x * v.x + v.y * v.y + v.z * v.z + v.w * v.w;
#pragma unroll
  for (int o = 32; o; o >>= 1) { s += __shfl_down(s, o); s2 += __shfl_down(s2, o); }
  __shared__ float rs[4], rs2[4];
  int wid = tid >> 6, lane = tid & 63;
  if (lane == 0) { rs[wid] = s; rs2[wid] = s2; }
  __syncthreads();
  s = rs[0] + rs[1] + rs[2] + rs[3];
  s2 = rs2[0] + rs2[1] + rs2[2] + rs2[3];
  float mean = s * (1.f / 1024.f);
  float var = s2 * (1.f / 1024.f) - mean * mean;
  float rstd = rsqrtf(var + 1e-5f);
  float4 gv = ((const float4*)g)[tid];
  float4 bv = ((const float4*)b)[tid];
  ushort4 o;
  o.x = f2bf((v.x - mean) * rstd * gv.x + bv.x);
  o.y = f2bf((v.y - mean) * rstd * gv.y + bv.y);
  o.z = f2bf((v.z - mean) * rstd * gv.z + bv.z);
  o.w = f2bf((v.w - mean) * rstd * gv.w + bv.w);
  ((ushort4*)out)[(size_t)row * 256 + tid] = o;
}

// depthwise conv k=3 pad=1 along t for Q (sel=0) and K (sel=1) from fused QKV buffer.
__global__ __launch_bounds__(128) void dwconv_qk_kernel(const u16* __restrict__ qkv,
                                                        const float* __restrict__ qc,
                                                        const float* __restrict__ kc,
                                                        u16* __restrict__ Qc,
                                                        u16* __restrict__ Kc)
{
  int sel = blockIdx.y;
  int row = blockIdx.x;     // b*1024 + t
  int t = row & 1023;
  int c0 = threadIdx.x * 8;
  const u16* r0 = qkv + (size_t)row * 3072 + (sel << 10) + c0;
  const float* wc = sel ? kc : qc;
  u16* dst = (sel ? Kc : Qc) + (size_t)row * 1024 + c0;
  u16x8 zv = {0, 0, 0, 0, 0, 0, 0, 0};
  u16x8 xm = zv, xp = zv;
  if (t > 0) xm = *(const u16x8*)(r0 - 3072);
  u16x8 xc = *(const u16x8*)r0;
  if (t < 1023) xp = *(const u16x8*)(r0 + 3072);
  u16x8 o;
#pragma unroll
  for (int j = 0; j < 8; ++j) {
    int c = c0 + j;
    float v = bf2f(xm[j]) * wc[c * 3 + 0] + bf2f(xc[j]) * wc[c * 3 + 1] + bf2f(xp[j]) * wc[c * 3 + 2];
    o[j] = f2bf(v);
  }
  *(u16x8*)dst = o;
}

// depthwise conv + transposed store for V: out[(b*4+c/256)][c%256][t] from qkv col 2048+c
__global__ __launch_bounds__(1024) void dwconv_t_kernel(const u16* __restrict__ qkv,
                                                        const float* __restrict__ wc,
                                                        u16* __restrict__ out)
{
  __shared__ float tile[32][33];
  int b = blockIdx.z;
  int t = blockIdx.x * 32 + threadIdx.y;
  int c = blockIdx.y * 32 + threadIdx.x;
  size_t base = ((size_t)b * 1024 + t) * 3072 + 2048 + c;
  float xm = (t > 0) ? bf2f(qkv[base - 3072]) : 0.f;
  float xc = bf2f(qkv[base]);
  float xp = (t < 1023) ? bf2f(qkv[base + 3072]) : 0.f;
  tile[threadIdx.y][threadIdx.x] = xm * wc[c * 3 + 0] + xc * wc[c * 3 + 1] + xp * wc[c * 3 + 2];
  __syncthreads();
  int c2 = blockIdx.y * 32 + threadIdx.y;
  int t2 = blockIdx.x * 32 + threadIdx.x;
  int z = b * 4 + (c2 >> 8);
  out[((size_t)z * 256 + (c2 & 255)) * 1024 + t2] = f2bf(tile[threadIdx.x][threadIdx.y]);
}

// row softmax over 1024, f32 in -> bf16 out
__global__ __launch_bounds__(256) void softmax_kernel(const float* __restrict__ qk,
                                                      u16* __restrict__ P)
{
  size_t row = blockIdx.x;
  int tid = threadIdx.x;
  float4 v = ((const float4*)(qk + row * 1024))[tid];
  float m = fmaxf(fmaxf(v.x, v.y), fmaxf(v.z, v.w));
#pragma unroll
  for (int o = 32; o; o >>= 1) m = fmaxf(m, __shfl_down(m, o));
  __shared__ float red[4];
  int wid = tid >> 6, lane = tid & 63;
  if (lane == 0) red[wid] = m;
  __syncthreads();
  m = fmaxf(fmaxf(red[0], red[1]), fmaxf(red[2], red[3]));
  float e0 = __expf(v.x - m), e1 = __expf(v.y - m), e2 = __expf(v.z - m), e3 = __expf(v.w - m);
  float s = e0 + e1 + e2 + e3;
#pragma unroll
  for (int o = 32; o; o >>= 1) s += __shfl_down(s, o);
  __syncthreads();
  if (lane == 0) red[wid] = s;
  __syncthreads();
  s = red[0] + red[1] + red[2] + red[3];
  float rinv = 1.f / s;
  ushort4 o;
  o.x = f2bf(e0 * rinv); o.y = f2bf(e1 * rinv); o.z = f2bf(e2 * rinv); o.w = f2bf(e3 * rinv);
  ((ushort4*)P)[row * 256 + tid] = o;
}

// 12 fused f32->bf16 casts of 1M elements each (weight prep, one launch)
struct CastJobs { const float* s[12]; u16* d[12]; };
__global__ __launch_bounds__(256) void cast12_kernel(CastJobs J)
{
  int j = blockIdx.y;
  int i = blockIdx.x * 256 + threadIdx.x;   // 262144 float4 per job
  float4 v = ((const float4*)J.s[j])[i];
  ushort4 o;
  o.x = f2bf(v.x); o.y = f2bf(v.y); o.z = f2bf(v.z); o.w = f2bf(v.w);
  ((ushort4*)J.d[j])[i] = o;
}

// pw [256][1024] f32 -> pwT [1024][256] bf16
__global__ __launch_bounds__(1024) void pwt_kernel(const float* __restrict__ pw,
                                                   u16* __restrict__ pwT)
{
  __shared__ float tile[32][33];
  int d = blockIdx.y * 32 + threadIdx.y;
  int t = blockIdx.x * 32 + threadIdx.x;
  tile[threadIdx.y][threadIdx.x] = pw[(size_t)d * 1024 + t];
  __syncthreads();
  int t2 = blockIdx.x * 32 + threadIdx.y;
  int d2 = blockIdx.y * 32 + threadIdx.x;
  pwT[(size_t)t2 * 256 + d2] = f2bf(tile[threadIdx.x][threadIdx.y]);
}

// out[b][h][w] = xs[b][w][h], f32
__global__ __launch_bounds__(1024) void tout_kernel(const float* __restrict__ xs,
                                                    float* __restrict__ out)
{
  __shared__ float tile[32][33];
  int b = blockIdx.z;
  int w = blockIdx.x * 32 + threadIdx.y;
  int h = blockIdx.y * 32 + threadIdx.x;
  tile[threadIdx.y][threadIdx.x] = xs[((size_t)b * 1024 + w) * 1024 + h];
  __syncthreads();
  int h2 = blockIdx.y * 32 + threadIdx.y;
  int w2 = blockIdx.x * 32 + threadIdx.x;
  out[((size_t)b * 1024 + h2) * 1024 + w2] = tile[threadIdx.x][threadIdx.y];
}

static void run_attn(hipStream_t stream, float* xs, const u16* qsrc, const u16* kvsrc, int asplit,
                     u16* QKVraw, u16* Qc, u16* Kc, u16* Vt, u16* P, u16* Am,
                     const u16* wqkv, const u16* wo, const u16* pwt,
                     const float* qc, const float* kc, const float* vc,
                     const float* prevqk, float* qko)
{
  dim3 blk(512);
  // fused QKV projection: M=4096, N=3072, K=1024. A per-column-block select.
  gemm256<EPI_BF16, false, 256><<<dim3(12, 32, 1), blk, 0, stream>>>(
      qsrc, kvsrc, asplit, 0, 0, 1024, nullptr, 0,
      wqkv, 0, 0, 1024, nullptr, 0, 0, 0,
      1024, 0, QKVraw, 0, 0, 3072, nullptr, 0, 0, 1.f);
  dwconv_qk_kernel<<<dim3(4096, 2), 128, 0, stream>>>(QKVraw, qc, kc, Qc, Kc);
  dwconv_t_kernel<<<dim3(32, 32, 4), dim3(32, 32), 0, stream>>>(QKVraw, vc, Vt);
  // qk = (Q Kt + pwT Qt)/32 + prev, K=512 split at 256. 16 batches (b,n).
  gemm256<EPI_QK, true, 256><<<dim3(4, 8, 16), blk, 0, stream>>>(
      Qc, Qc, 1 << 30, 1048576, 256, 1024, pwt, 256,
      Kc, 1048576, 256, 1024, Qc, 1048576, 256, 1024,
      512, 256, qko, 4194304, 1048576, 1024, prevqk, 1048576, 1024, 0.03125f);
  softmax_kernel<<<16384, 256, 0, stream>>>(qko, P);
  // PV: per z, [1024x1024]x[1024x256] — BN=128 (256 blocks)
  gemm256<EPI_BF16, false, 128><<<dim3(2, 8, 16), blk, 0, stream>>>(
      P, P, 1 << 30, 4194304, 1048576, 1024, nullptr, 0,
      Vt, 1048576, 262144, 1024, nullptr, 0, 0, 0,
      1024, 0, Am, 1048576, 256, 1024, nullptr, 0, 0, 1.f);
  // O-proj + residual add into xs (f32) — BN=128 (256 blocks)
  gemm256<EPI_ADDF32, false, 128><<<dim3(8, 32, 1), blk, 0, stream>>>(
      Am, Am, 1 << 30, 0, 0, 1024, nullptr, 0,
      wo, 0, 0, 1024, nullptr, 0, 0, 0,
      1024, 0, xs, 0, 0, 1024, nullptr, 0, 0, 1.f);
}

extern "C" void kernel_launch(void* const* d_in, const int* in_sizes, int n_in,
                              void* d_out, int out_size, void* d_ws, size_t ws_size,
                              hipStream_t stream)
{
  (void)in_sizes; (void)n_in; (void)out_size; (void)ws_size;
  const float* x    = (const float*)d_in[0];
  const float* memp = (const float*)d_in[1];
  const float* pqk1 = (const float*)d_in[2];
  const float* pqk2 = (const float*)d_in[3];
  const float* ip_w = (const float*)d_in[4];
  const float* ip_b = (const float*)d_in[5];
  const float* mp_w = (const float*)d_in[6];
  const float* mp_b = (const float*)d_in[7];
  const float* ln1g = (const float*)d_in[8];
  const float* ln1b = (const float*)d_in[9];
  const float* ln2g = (const float*)d_in[10];
  const float* ln2b = (const float*)d_in[11];
  const float* ln3g = (const float*)d_in[12];
  const float* ln3b = (const float*)d_in[13];
  const float* a1qw = (const float*)d_in[14];
  const float* a1qc = (const float*)d_in[15];
  const float* a1kw = (const float*)d_in[16];
  const float* a1kc = (const float*)d_in[17];
  const float* a1vw = (const float*)d_in[18];
  const float* a1vc = (const float*)d_in[19];
  const float* a1ow = (const float*)d_in[20];
  const float* a1pw = (const float*)d_in[21];
  const float* a2qw = (const float*)d_in[22];
  const float* a2qc = (const float*)d_in[23];
  const float* a2kw = (const float*)d_in[24];
  const float* a2kc = (const float*)d_in[25];
  const float* a2vw = (const float*)d_in[26];
  const float* a2vc = (const float*)d_in[27];
  const float* a2ow = (const float*)d_in[28];
  const float* a2pw = (const float*)d_in[29];
  const float* l1w  = (const float*)d_in[30];
  const float* l2w  = (const float*)d_in[31];

  float* outp = (float*)d_out;
  float* qk1o = outp + 4194304;    // [4][4][1024][1024]
  float* qk2o = outp + 20971520;

  const size_t MB = 1024 * 1024;
  char* W = (char*)d_ws;
  float* xs   = (float*)(W);             // 16MB f32 [4][1024w][1024h]
  u16* msb    = (u16*)(W + 16 * MB);     // 8MB bf16
  u16* xln    = (u16*)(W + 24 * MB);     // 8MB
  u16* QKVraw = (u16*)(W + 32 * MB);     // 24MB [4096][3072]
  u16* Qc     = (u16*)(W + 56 * MB);     // 8MB
  u16* Kc     = (u16*)(W + 64 * MB);     // 8MB
  u16* Vt     = (u16*)(W + 72 * MB);     // 8MB  [16][256][1024]
  u16* P      = (u16*)(W + 80 * MB);     // 32MB [16][1024][1024]
  u16* Am     = (u16*)(W + 112 * MB);    // 8MB
  u16* wqkv1  = (u16*)(W + 120 * MB);    // 6MB [3072][1024]
  u16* wqkv2  = (u16*)(W + 126 * MB);    // 6MB
  u16* wo1    = (u16*)(W + 132 * MB);    // 2MB
  u16* wo2    = (u16*)(W + 134 * MB);    // 2MB
  u16* wl1    = (u16*)(W + 136 * MB);    // 4MB [2048][1024]
  u16* wl2    = (u16*)(W + 140 * MB);    // 4MB [1024][2048]
  u16* pwt1   = (u16*)(W + 144 * MB);    // 0.5MB [1024][256]
  u16* pwt2   = (u16*)(W + 144 * MB + 512 * 1024);
  u16* H1     = QKVraw;                  // 16MB overlay (dead in FFN)

  // weight prep: one fused cast launch + 2 pw transposes
  CastJobs J;
  J.s[0] = a1qw; J.d[0] = wqkv1;
  J.s[1] = a1kw; J.d[1] = wqkv1 + 1048576;
  J.s[2] = a1vw; J.d[2] = wqkv1 + 2097152;
  J.s[3] = a2qw; J.d[3] = wqkv2;
  J.s[4] = a2kw; J.d[4] = wqkv2 + 1048576;
  J.s[5] = a2vw; J.d[5] = wqkv2 + 2097152;
  J.s[6] = a1ow; J.d[6] = wo1;
  J.s[7] = a2ow; J.d[7] = wo2;
  J.s[8] = l1w;            J.d[8] = wl1;
  J.s[9] = l1w + 1048576;  J.d[9] = wl1 + 1048576;
  J.s[10] = l2w;           J.d[10] = wl2;
  J.s[11] = l2w + 1048576; J.d[11] = wl2 + 1048576;
  cast12_kernel<<<dim3(1024, 12), 256, 0, stream>>>(J);
  pwt_kernel<<<dim3(32, 8, 1), dim3(32, 32), 0, stream>>>(a1pw, pwt1);
  pwt_kernel<<<dim3(32, 8, 1), dim3(32, 32), 0, stream>>>(a2pw, pwt2);

  // input projections: full-row contiguous reads, LDS transpose
  proj3_kernel<<<dim3(64, 4, 2), 1024, 0, stream>>>(
      x, memp, ip_w, ip_b, mp_w, mp_b, xs, msb);

  // attention 1 (self): q and kv both from LN1(xs)
  ln_kernel<<<4096, 256, 0, stream>>>(xs, ln1g, ln1b, xln);
  run_attn(stream, xs, xln, xln, 1 << 30, QKVraw, Qc, Kc, Vt, P, Am,
           wqkv1, wo1, pwt1, a1qc, a1kc, a1vc, pqk1, qk1o);

  // attention 2 (cross): q from LN2(xs), kv from ms
  ln_kernel<<<4096, 256, 0, stream>>>(xs, ln2g, ln2b, xln);
  run_attn(stream, xs, xln, msb, 1024, QKVraw, Qc, Kc, Vt, P, Am,
           wqkv2, wo2, pwt2, a2qc, a2kc, a2vc, pqk2, qk2o);

  // FFN
  ln_kernel<<<4096, 256, 0, stream>>>(xs, ln3g, ln3b, xln);
  gemm256<EPI_RELU2, false, 256><<<dim3(8, 32, 1), dim3(512), 0, stream>>>(
      xln, xln, 1 << 30, 0, 0, 1024, nullptr, 0,
      wl1, 0, 0, 1024, nullptr, 0, 0, 0,
      1024, 0, H1, 0, 0, 2048, nullptr, 0, 0, 1.f);
  gemm256<EPI_ADDF32, false, 128><<<dim3(8, 32, 1), dim3(512), 0, stream>>>(
      H1, H1, 1 << 30, 0, 0, 2048, nullptr, 0,
      wl2, 0, 0, 2048, nullptr, 0, 0, 0,
      2048, 0, xs, 0, 0, 1024, nullptr, 0, 0, 1.f);

  // final transpose to out[b][1][bins][w]
  tout_kernel<<<dim3(32, 32, 4), dim3(32, 32), 0, stream>>>(xs, outp);
}

// Round 7
// 503.051 us; speedup vs baseline: 1.4254x; 1.0243x over previous
//
#include <hip/hip_runtime.h>
#include <stdint.h>

typedef unsigned short u16;
typedef __bf16 bfv8 __attribute__((ext_vector_type(8)));
typedef float f32x4 __attribute__((ext_vector_type(4)));
typedef unsigned short u16x8 __attribute__((ext_vector_type(8)));

#define DI __device__ __forceinline__

DI u16 f2bf(float f) {
  union { float f; unsigned u; } c; c.f = f;
  unsigned r = c.u + 0x7FFFu + ((c.u >> 16) & 1u);
  return (u16)(r >> 16);
}
DI float bf2f(u16 b) {
  union { unsigned u; float f; } c; c.u = ((unsigned)b) << 16;
  return c.f;
}

enum { EPI_BF16 = 0, EPI_RELU2 = 1, EPI_ADDF32 = 2, EPI_QK = 3 };

#define GLDS(g, l)                                                              \
  __builtin_amdgcn_global_load_lds((const __attribute__((address_space(1))) void*)(g), \
                                   (__attribute__((address_space(3))) void*)(l), 16, 0, 0)

#define VMCNT_BAR(N)                                        \
  do {                                                      \
    asm volatile("s_waitcnt vmcnt(" #N ")" ::: "memory");   \
    __builtin_amdgcn_sched_barrier(0);                      \
    __builtin_amdgcn_s_barrier();                           \
    __builtin_amdgcn_sched_barrier(0);                      \
  } while (0)

#define BAR_ONLY()                                          \
  do {                                                      \
    __builtin_amdgcn_sched_barrier(0);                      \
    __builtin_amdgcn_s_barrier();                           \
    __builtin_amdgcn_sched_barrier(0);                      \
  } while (0)

// C[m,n] = sum_k A[m,k]*B[n,k]. Tile 128xBN (BN=128|256), BK=64, 512 thr
// (8 waves, 2Mx4N), 3-stage LDS pipeline with counted vmcnt + setprio.
// Bijective chunked XCD swizzle (m204). LDS XOR swizzle round-1-verified.
template <int EPI, bool KSPLIT, int BN>
__global__ __launch_bounds__(512) void gemm256(
    const u16* __restrict__ Aq, const u16* __restrict__ Akv, int asplit,
    long a1q, long a1r, int lda1,
    const u16* __restrict__ A2, int lda2,
    const u16* __restrict__ B1, long b1q, long b1r, int ldb1,
    const u16* __restrict__ B2, long b2q, long b2r, int ldb2,
    int K, int ksp,
    void* __restrict__ Cv, long cq, long cr, int ldc,
    const float* __restrict__ extra, long eq, int lde,
    float scale)
{
  constexpr int NJ = BN / 64;
  constexpr int NBL = BN / 64;
  constexpr int SS = 8192 + BN * 64;
  constexpr int LPS = 2 + NBL;
  __shared__ __align__(16) u16 lds[3 * SS];
  const int tid = threadIdx.x;
  const int wid = tid >> 6, lane = tid & 63;

  const int gx = gridDim.x, gy = gridDim.y;
  const int nwg = gx * gy * (int)gridDim.z;
  const int flat = blockIdx.x + gx * (blockIdx.y + gy * blockIdx.z);
  const int q = nwg >> 3, r = nwg & 7;
  const int xcd = flat & 7, idx = flat >> 3;
  const int wg = (xcd < r ? xcd * (q + 1) : r * (q + 1) + (xcd - r) * q) + idx;
  const int bx = wg % gx;
  const int tmp = wg / gx;
  const int by = tmp % gy;
  const int bz = tmp / gy;

  const long zq = bz >> 2, zr = bz & 3;
  const int m0 = by * 128, n0 = bx * BN;
  const u16* Ab = ((n0 >= asplit) ? Akv : Aq) + zq * a1q + zr * a1r;
  const u16* Bb = B1 + zq * b1q + zr * b1r;
  const u16* B2b = KSPLIT ? (B2 + zq * b2q + zr * b2r) : (const u16*)nullptr;
  const int wm = (wid >> 2) * 64, wn = (wid & 3) * (BN / 4);
  const int fr = lane & 15, fq = lane >> 4;

  f32x4 acc[4][NJ];
#pragma unroll
  for (int i = 0; i < 4; ++i)
#pragma unroll
    for (int j = 0; j < NJ; ++j)
      acc[i][j] = (f32x4){0.f, 0.f, 0.f, 0.f};

  const int nt = K >> 6;

  auto STAGE = [&](int tt, int sb) {
    const int k0 = tt << 6;
    u16* Ld = &lds[sb * SS];
    const u16* Asrc; int la; const u16* Bsrc; int lb;
    if (!KSPLIT || k0 < ksp) { Asrc = Ab + k0; la = lda1; Bsrc = Bb + k0; lb = ldb1; }
    else { Asrc = A2 + (k0 - ksp); la = lda2; Bsrc = B2b + (k0 - ksp); lb = ldb2; }
#pragma unroll
    for (int l = 0; l < 2; ++l) {
      int idx2 = (l << 9) + tid;
      int row = idx2 >> 3;
      int sc = ((idx2 & 7) ^ (row & 7)) << 3;
      GLDS(Asrc + (size_t)(m0 + row) * la + sc,
           Ld + (((l << 3) + wid) << 9));
    }
#pragma unroll
    for (int l = 0; l < NBL; ++l) {
      int idx2 = (l << 9) + tid;
      int row = idx2 >> 3;
      int sc = ((idx2 & 7) ^ (row & 7)) << 3;
      GLDS(Bsrc + (size_t)(n0 + row) * lb + sc,
           Ld + 8192 + (((l << 3) + wid) << 9));
    }
  };

  auto COMPUTE = [&](int cb) {
    const u16* As = &lds[cb * SS];
    const u16* Bs = As + 8192;
#pragma unroll
    for (int ks = 0; ks < 2; ++ks) {
      bfv8 av[4];
#pragma unroll
      for (int i = 0; i < 4; ++i) {
        int ra = wm + i * 16 + fr;
        int ca = (((ks << 2) + fq) ^ (ra & 7)) << 3;
        av[i] = *(const bfv8*)&As[(ra << 6) + ca];
      }
#pragma unroll
      for (int nh = 0; nh < NJ / 2; ++nh) {
        bfv8 bv[2];
#pragma unroll
        for (int j = 0; j < 2; ++j) {
          int rb = wn + (nh << 5) + (j << 4) + fr;
          int cb2 = (((ks << 2) + fq) ^ (rb & 7)) << 3;
          bv[j] = *(const bfv8*)&Bs[(rb << 6) + cb2];
        }
        __builtin_amdgcn_s_setprio(1);
#pragma unroll
        for (int i = 0; i < 4; ++i) {
          acc[i][(nh << 1)] = __builtin_amdgcn_mfma_f32_16x16x32_bf16(av[i], bv[0], acc[i][(nh << 1)], 0, 0, 0);
          acc[i][(nh << 1) + 1] = __builtin_amdgcn_mfma_f32_16x16x32_bf16(av[i], bv[1], acc[i][(nh << 1) + 1], 0, 0, 0);
        }
        __builtin_amdgcn_s_setprio(0);
      }
    }
  };

  STAGE(0, 0);
  STAGE(1, 1);
  if constexpr (LPS == 6) VMCNT_BAR(6); else VMCNT_BAR(4);
  int cur = 0;
  for (int t = 0; t < nt; ++t) {
    if (t + 2 < nt) {
      int stg = cur + 2; if (stg >= 3) stg -= 3;
      STAGE(t + 2, stg);
      COMPUTE(cur);
      if constexpr (LPS == 6) VMCNT_BAR(6); else VMCNT_BAR(4);
    } else if (t + 1 < nt) {
      COMPUTE(cur);
      VMCNT_BAR(0);
    } else {
      COMPUTE(cur);
    }
    cur = (cur == 2) ? 0 : cur + 1;
  }

  if constexpr (EPI == EPI_BF16 || EPI == EPI_RELU2) {
    u16* Cb = (u16*)Cv + zq * cq + zr * cr;
#pragma unroll
    for (int i = 0; i < 4; ++i)
#pragma unroll
      for (int j = 0; j < NJ; ++j)
#pragma unroll
        for (int r2 = 0; r2 < 4; ++r2) {
          int row = m0 + wm + i * 16 + (fq << 2) + r2;
          int col = n0 + wn + j * 16 + fr;
          float v = acc[i][j][r2];
          if constexpr (EPI == EPI_RELU2) { v = fmaxf(v, 0.f); v = v * v; }
          Cb[(size_t)row * ldc + col] = f2bf(v);
        }
  } else if constexpr (EPI == EPI_ADDF32) {
    float* Cb = (float*)Cv + zq * cq + zr * cr;
#pragma unroll
    for (int i = 0; i < 4; ++i)
#pragma unroll
      for (int j = 0; j < NJ; ++j)
#pragma unroll
        for (int r2 = 0; r2 < 4; ++r2) {
          int row = m0 + wm + i * 16 + (fq << 2) + r2;
          int col = n0 + wn + j * 16 + fr;
          Cb[(size_t)row * ldc + col] += acc[i][j][r2];
        }
  } else {  // EPI_QK
    float* Cb = (float*)Cv + zq * cq + zr * cr;
    const float* Eb = extra + (size_t)bz * eq;
#pragma unroll
    for (int i = 0; i < 4; ++i)
#pragma unroll
      for (int j = 0; j < NJ; ++j)
#pragma unroll
        for (int r2 = 0; r2 < 4; ++r2) {
          int row = m0 + wm + i * 16 + (fq << 2) + r2;
          int col = n0 + wn + j * 16 + fr;
          Cb[(size_t)row * ldc + col] = acc[i][j][r2] * scale + Eb[(size_t)row * lde + col];
        }
  }
}

// Input projection via global_load_lds DMA staging (read-path A/B test).
// Block = 256 thr (4 waves). Tile = (task,b, 16 h-rows, 256 w-cols).
// Per channel: 16 rows x 1KB DMA'd into LDS (4 loads/wave; per-lane source
// addr = row base + lane*16B — REQUIRED, src addr is per-lane, m104),
// double-buffered across channels with counted vmcnt(4); accumulate from
// LDS (stride-1 across lanes, conflict-free). Channel order rotated per
// block to decorrelate the 8 DRAM streams.
__global__ __launch_bounds__(256) void proj4_kernel(const float* __restrict__ x,
                                                    const float* __restrict__ memp,
                                                    const float* __restrict__ ipw,
                                                    const float* __restrict__ ipb,
                                                    const float* __restrict__ mpw,
                                                    const float* __restrict__ mpb,
                                                    float* __restrict__ xs,
                                                    u16* __restrict__ msb)
{
  __shared__ __align__(16) float sbuf[2][16][256];   // 32 KB
  const int t = threadIdx.x;
  const int wid = t >> 6, lane = t & 63;
  const int task = blockIdx.z >> 2;
  const int b = blockIdx.z & 3;
  const int h0 = blockIdx.x << 4;
  const int w0 = blockIdx.y << 8;
  const float* src = task ? memp : x;
  const float* w8 = task ? mpw : ipw;
  const float bias = task ? mpb[0] : ipb[0];
  const int crot = (blockIdx.x + blockIdx.y + blockIdx.z) & 7;
  // pre-rotated weights: wr[i] pairs with staged channel (i+crot)&7; static reg idx
  float wr[8];
#pragma unroll
  for (int j = 0; j < 8; ++j) wr[j] = w8[(j + crot) & 7];
  float acc[16];
#pragma unroll
  for (int h = 0; h < 16; ++h) acc[h] = bias;
  const size_t bbase = ((size_t)b * 8) << 20;

  auto STAGE_C = [&](int i, int sb) {
    const int c = (i + crot) & 7;
    // per-lane source: lane covers bytes [lane*16, lane*16+16) of each 1KB row
    const float* g = src + bbase + ((size_t)c << 20) + (size_t)h0 * 1024 + w0 + (lane << 2);
#pragma unroll
    for (int l = 0; l < 4; ++l) {
      int row = (wid << 2) + l;
      GLDS(g + (size_t)row * 1024, &sbuf[sb][row][0]);
    }
  };

  STAGE_C(0, 0);
  STAGE_C(1, 1);
#pragma unroll
  for (int i = 0; i < 8; ++i) {
    if (i < 7) VMCNT_BAR(4); else VMCNT_BAR(0);
    {
      const float wc = wr[i];
      const int sb = i & 1;
#pragma unroll
      for (int h = 0; h < 16; ++h)
        acc[h] += sbuf[sb][h][t] * wc;
    }
    BAR_ONLY();
    if (i + 2 < 8) STAGE_C(i + 2, i & 1);
  }

  if (task) {
    u16* d = &msb[((size_t)b * 1024 + w0 + t) * 1024 + h0];
    u16x8 o0, o1;
#pragma unroll
    for (int h = 0; h < 8; ++h) { o0[h] = f2bf(acc[h]); o1[h] = f2bf(acc[h + 8]); }
    *(u16x8*)&d[0] = o0;
    *(u16x8*)&d[8] = o1;
  } else {
    float* d = &xs[((size_t)b * 1024 + w0 + t) * 1024 + h0];
#pragma unroll
    for (int p = 0; p < 4; ++p) {
      f32x4 v = {acc[p * 4], acc[p * 4 + 1], acc[p * 4 + 2], acc[p * 4 + 3]};
      *(f32x4*)&d[p * 4] = v;
    }
  }
}

// LayerNorm over 1024, f32 in -> bf16 out. one block per row.
__global__ __launch_bounds__(256) void ln_kernel(const float* __restrict__ x,
                                                 const float* __restrict__ g,
                                                 const float* __restrict__ b,
                                                 u16* __restrict__ out)
{
  int row = blockIdx.x, tid = threadIdx.x;
  float4 v = ((const float4*)(x + (size_t)row * 1024))[tid];
  float s = v.x + v.y + v.z + v.w;
  float s2 = v.x * v.x + v.y * v.y + v.z * v.z + v.w * v.w;
#pragma unroll
  for (int o = 32; o; o >>= 1) { s += __shfl_down(s, o); s2 += __shfl_down(s2, o); }
  __shared__ float rs[4], rs2[4];
  int wid = tid >> 6, lane = tid & 63;
  if (lane == 0) { rs[wid] = s; rs2[wid] = s2; }
  __syncthreads();
  s = rs[0] + rs[1] + rs[2] + rs[3];
  s2 = rs2[0] + rs2[1] + rs2[2] + rs2[3];
  float mean = s * (1.f / 1024.f);
  float var = s2 * (1.f / 1024.f) - mean * mean;
  float rstd = rsqrtf(var + 1e-5f);
  float4 gv = ((const float4*)g)[tid];
  float4 bv = ((const float4*)b)[tid];
  ushort4 o;
  o.x = f2bf((v.x - mean) * rstd * gv.x + bv.x);
  o.y = f2bf((v.y - mean) * rstd * gv.y + bv.y);
  o.z = f2bf((v.z - mean) * rstd * gv.z + bv.z);
  o.w = f2bf((v.w - mean) * rstd * gv.w + bv.w);
  ((ushort4*)out)[(size_t)row * 256 + tid] = o;
}

// depthwise conv k=3 pad=1 along t for Q (sel=0) and K (sel=1) from fused QKV buffer.
__global__ __launch_bounds__(128) void dwconv_qk_kernel(const u16* __restrict__ qkv,
                                                        const float* __restrict__ qc,
                                                        const float* __restrict__ kc,
                                                        u16* __restrict__ Qc,
                                                        u16* __restrict__ Kc)
{
  int sel = blockIdx.y;
  int row = blockIdx.x;     // b*1024 + t
  int t = row & 1023;
  int c0 = threadIdx.x * 8;
  const u16* r0 = qkv + (size_t)row * 3072 + (sel << 10) + c0;
  const float* wc = sel ? kc : qc;
  u16* dst = (sel ? Kc : Qc) + (size_t)row * 1024 + c0;
  u16x8 zv = {0, 0, 0, 0, 0, 0, 0, 0};
  u16x8 xm = zv, xp = zv;
  if (t > 0) xm = *(const u16x8*)(r0 - 3072);
  u16x8 xc = *(const u16x8*)r0;
  if (t < 1023) xp = *(const u16x8*)(r0 + 3072);
  u16x8 o;
#pragma unroll
  for (int j = 0; j < 8; ++j) {
    int c = c0 + j;
    float v = bf2f(xm[j]) * wc[c * 3 + 0] + bf2f(xc[j]) * wc[c * 3 + 1] + bf2f(xp[j]) * wc[c * 3 + 2];
    o[j] = f2bf(v);
  }
  *(u16x8*)dst = o;
}

// depthwise conv + transposed store for V: out[(b*4+c/256)][c%256][t] from qkv col 2048+c
__global__ __launch_bounds__(1024) void dwconv_t_kernel(const u16* __restrict__ qkv,
                                                        const float* __restrict__ wc,
                                                        u16* __restrict__ out)
{
  __shared__ float tile[32][33];
  int b = blockIdx.z;
  int t = blockIdx.x * 32 + threadIdx.y;
  int c = blockIdx.y * 32 + threadIdx.x;
  size_t base = ((size_t)b * 1024 + t) * 3072 + 2048 + c;
  float xm = (t > 0) ? bf2f(qkv[base - 3072]) : 0.f;
  float xc = bf2f(qkv[base]);
  float xp = (t < 1023) ? bf2f(qkv[base + 3072]) : 0.f;
  tile[threadIdx.y][threadIdx.x] = xm * wc[c * 3 + 0] + xc * wc[c * 3 + 1] + xp * wc[c * 3 + 2];
  __syncthreads();
  int c2 = blockIdx.y * 32 + threadIdx.y;
  int t2 = blockIdx.x * 32 + threadIdx.x;
  int z = b * 4 + (c2 >> 8);
  out[((size_t)z * 256 + (c2 & 255)) * 1024 + t2] = f2bf(tile[threadIdx.x][threadIdx.y]);
}

// row softmax over 1024, f32 in -> bf16 out
__global__ __launch_bounds__(256) void softmax_kernel(const float* __restrict__ qk,
                                                      u16* __restrict__ P)
{
  size_t row = blockIdx.x;
  int tid = threadIdx.x;
  float4 v = ((const float4*)(qk + row * 1024))[tid];
  float m = fmaxf(fmaxf(v.x, v.y), fmaxf(v.z, v.w));
#pragma unroll
  for (int o = 32; o; o >>= 1) m = fmaxf(m, __shfl_down(m, o));
  __shared__ float red[4];
  int wid = tid >> 6, lane = tid & 63;
  if (lane == 0) red[wid] = m;
  __syncthreads();
  m = fmaxf(fmaxf(red[0], red[1]), fmaxf(red[2], red[3]));
  float e0 = __expf(v.x - m), e1 = __expf(v.y - m), e2 = __expf(v.z - m), e3 = __expf(v.w - m);
  float s = e0 + e1 + e2 + e3;
#pragma unroll
  for (int o = 32; o; o >>= 1) s += __shfl_down(s, o);
  __syncthreads();
  if (lane == 0) red[wid] = s;
  __syncthreads();
  s = red[0] + red[1] + red[2] + red[3];
  float rinv = 1.f / s;
  ushort4 o;
  o.x = f2bf(e0 * rinv); o.y = f2bf(e1 * rinv); o.z = f2bf(e2 * rinv); o.w = f2bf(e3 * rinv);
  ((ushort4*)P)[row * 256 + tid] = o;
}

// 12 fused f32->bf16 casts of 1M elements each (weight prep, one launch)
struct CastJobs { const float* s[12]; u16* d[12]; };
__global__ __launch_bounds__(256) void cast12_kernel(CastJobs J)
{
  int j = blockIdx.y;
  int i = blockIdx.x * 256 + threadIdx.x;   // 262144 float4 per job
  float4 v = ((const float4*)J.s[j])[i];
  ushort4 o;
  o.x = f2bf(v.x); o.y = f2bf(v.y); o.z = f2bf(v.z); o.w = f2bf(v.w);
  ((ushort4*)J.d[j])[i] = o;
}

// pw [256][1024] f32 -> pwT [1024][256] bf16
__global__ __launch_bounds__(1024) void pwt_kernel(const float* __restrict__ pw,
                                                   u16* __restrict__ pwT)
{
  __shared__ float tile[32][33];
  int d = blockIdx.y * 32 + threadIdx.y;
  int t = blockIdx.x * 32 + threadIdx.x;
  tile[threadIdx.y][threadIdx.x] = pw[(size_t)d * 1024 + t];
  __syncthreads();
  int t2 = blockIdx.x * 32 + threadIdx.y;
  int d2 = blockIdx.y * 32 + threadIdx.x;
  pwT[(size_t)t2 * 256 + d2] = f2bf(tile[threadIdx.x][threadIdx.y]);
}

// out[b][h][w] = xs[b][w][h], f32
__global__ __launch_bounds__(1024) void tout_kernel(const float* __restrict__ xs,
                                                    float* __restrict__ out)
{
  __shared__ float tile[32][33];
  int b = blockIdx.z;
  int w = blockIdx.x * 32 + threadIdx.y;
  int h = blockIdx.y * 32 + threadIdx.x;
  tile[threadIdx.y][threadIdx.x] = xs[((size_t)b * 1024 + w) * 1024 + h];
  __syncthreads();
  int h2 = blockIdx.y * 32 + threadIdx.y;
  int w2 = blockIdx.x * 32 + threadIdx.x;
  out[((size_t)b * 1024 + h2) * 1024 + w2] = tile[threadIdx.x][threadIdx.y];
}

static void run_attn(hipStream_t stream, float* xs, const u16* qsrc, const u16* kvsrc, int asplit,
                     u16* QKVraw, u16* Qc, u16* Kc, u16* Vt, u16* P, u16* Am,
                     const u16* wqkv, const u16* wo, const u16* pwt,
                     const float* qc, const float* kc, const float* vc,
                     const float* prevqk, float* qko)
{
  dim3 blk(512);
  gemm256<EPI_BF16, false, 256><<<dim3(12, 32, 1), blk, 0, stream>>>(
      qsrc, kvsrc, asplit, 0, 0, 1024, nullptr, 0,
      wqkv, 0, 0, 1024, nullptr, 0, 0, 0,
      1024, 0, QKVraw, 0, 0, 3072, nullptr, 0, 0, 1.f);
  dwconv_qk_kernel<<<dim3(4096, 2), 128, 0, stream>>>(QKVraw, qc, kc, Qc, Kc);
  dwconv_t_kernel<<<dim3(32, 32, 4), dim3(32, 32), 0, stream>>>(QKVraw, vc, Vt);
  gemm256<EPI_QK, true, 256><<<dim3(4, 8, 16), blk, 0, stream>>>(
      Qc, Qc, 1 << 30, 1048576, 256, 1024, pwt, 256,
      Kc, 1048576, 256, 1024, Qc, 1048576, 256, 1024,
      512, 256, qko, 4194304, 1048576, 1024, prevqk, 1048576, 1024, 0.03125f);
  softmax_kernel<<<16384, 256, 0, stream>>>(qko, P);
  gemm256<EPI_BF16, false, 128><<<dim3(2, 8, 16), blk, 0, stream>>>(
      P, P, 1 << 30, 4194304, 1048576, 1024, nullptr, 0,
      Vt, 1048576, 262144, 1024, nullptr, 0, 0, 0,
      1024, 0, Am, 1048576, 256, 1024, nullptr, 0, 0, 1.f);
  gemm256<EPI_ADDF32, false, 128><<<dim3(8, 32, 1), blk, 0, stream>>>(
      Am, Am, 1 << 30, 0, 0, 1024, nullptr, 0,
      wo, 0, 0, 1024, nullptr, 0, 0, 0,
      1024, 0, xs, 0, 0, 1024, nullptr, 0, 0, 1.f);
}

extern "C" void kernel_launch(void* const* d_in, const int* in_sizes, int n_in,
                              void* d_out, int out_size, void* d_ws, size_t ws_size,
                              hipStream_t stream)
{
  (void)in_sizes; (void)n_in; (void)out_size; (void)ws_size;
  const float* x    = (const float*)d_in[0];
  const float* memp = (const float*)d_in[1];
  const float* pqk1 = (const float*)d_in[2];
  const float* pqk2 = (const float*)d_in[3];
  const float* ip_w = (const float*)d_in[4];
  const float* ip_b = (const float*)d_in[5];
  const float* mp_w = (const float*)d_in[6];
  const float* mp_b = (const float*)d_in[7];
  const float* ln1g = (const float*)d_in[8];
  const float* ln1b = (const float*)d_in[9];
  const float* ln2g = (const float*)d_in[10];
  const float* ln2b = (const float*)d_in[11];
  const float* ln3g = (const float*)d_in[12];
  const float* ln3b = (const float*)d_in[13];
  const float* a1qw = (const float*)d_in[14];
  const float* a1qc = (const float*)d_in[15];
  const float* a1kw = (const float*)d_in[16];
  const float* a1kc = (const float*)d_in[17];
  const float* a1vw = (const float*)d_in[18];
  const float* a1vc = (const float*)d_in[19];
  const float* a1ow = (const float*)d_in[20];
  const float* a1pw = (const float*)d_in[21];
  const float* a2qw = (const float*)d_in[22];
  const float* a2qc = (const float*)d_in[23];
  const float* a2kw = (const float*)d_in[24];
  const float* a2kc = (const float*)d_in[25];
  const float* a2vw = (const float*)d_in[26];
  const float* a2vc = (const float*)d_in[27];
  const float* a2ow = (const float*)d_in[28];
  const float* a2pw = (const float*)d_in[29];
  const float* l1w  = (const float*)d_in[30];
  const float* l2w  = (const float*)d_in[31];

  float* outp = (float*)d_out;
  float* qk1o = outp + 4194304;    // [4][4][1024][1024]
  float* qk2o = outp + 20971520;

  const size_t MB = 1024 * 1024;
  char* W = (char*)d_ws;
  float* xs   = (float*)(W);             // 16MB f32 [4][1024w][1024h]
  u16* msb    = (u16*)(W + 16 * MB);     // 8MB bf16
  u16* xln    = (u16*)(W + 24 * MB);     // 8MB
  u16* QKVraw = (u16*)(W + 32 * MB);     // 24MB [4096][3072]
  u16* Qc     = (u16*)(W + 56 * MB);     // 8MB
  u16* Kc     = (u16*)(W + 64 * MB);     // 8MB
  u16* Vt     = (u16*)(W + 72 * MB);     // 8MB  [16][256][1024]
  u16* P      = (u16*)(W + 80 * MB);     // 32MB [16][1024][1024]
  u16* Am     = (u16*)(W + 112 * MB);    // 8MB
  u16* wqkv1  = (u16*)(W + 120 * MB);    // 6MB [3072][1024]
  u16* wqkv2  = (u16*)(W + 126 * MB);    // 6MB
  u16* wo1    = (u16*)(W + 132 * MB);    // 2MB
  u16* wo2    = (u16*)(W + 134 * MB);    // 2MB
  u16* wl1    = (u16*)(W + 136 * MB);    // 4MB [2048][1024]
  u16* wl2    = (u16*)(W + 140 * MB);    // 4MB [1024][2048]
  u16* pwt1   = (u16*)(W + 144 * MB);    // 0.5MB [1024][256]
  u16* pwt2   = (u16*)(W + 144 * MB + 512 * 1024);
  u16* H1     = QKVraw;                  // 16MB overlay (dead in FFN)

  CastJobs J;
  J.s[0] = a1qw; J.d[0] = wqkv1;
  J.s[1] = a1kw; J.d[1] = wqkv1 + 1048576;
  J.s[2] = a1vw; J.d[2] = wqkv1 + 2097152;
  J.s[3] = a2qw; J.d[3] = wqkv2;
  J.s[4] = a2kw; J.d[4] = wqkv2 + 1048576;
  J.s[5] = a2vw; J.d[5] = wqkv2 + 2097152;
  J.s[6] = a1ow; J.d[6] = wo1;
  J.s[7] = a2ow; J.d[7] = wo2;
  J.s[8] = l1w;            J.d[8] = wl1;
  J.s[9] = l1w + 1048576;  J.d[9] = wl1 + 1048576;
  J.s[10] = l2w;           J.d[10] = wl2;
  J.s[11] = l2w + 1048576; J.d[11] = wl2 + 1048576;
  cast12_kernel<<<dim3(1024, 12), 256, 0, stream>>>(J);
  pwt_kernel<<<dim3(32, 8, 1), dim3(32, 32), 0, stream>>>(a1pw, pwt1);
  pwt_kernel<<<dim3(32, 8, 1), dim3(32, 32), 0, stream>>>(a2pw, pwt2);

  // input projections: DMA-staged (global_load_lds) read path
  proj4_kernel<<<dim3(64, 4, 8), 256, 0, stream>>>(
      x, memp, ip_w, ip_b, mp_w, mp_b, xs, msb);

  // attention 1 (self): q and kv both from LN1(xs)
  ln_kernel<<<4096, 256, 0, stream>>>(xs, ln1g, ln1b, xln);
  run_attn(stream, xs, xln, xln, 1 << 30, QKVraw, Qc, Kc, Vt, P, Am,
           wqkv1, wo1, pwt1, a1qc, a1kc, a1vc, pqk1, qk1o);

  // attention 2 (cross): q from LN2(xs), kv from ms
  ln_kernel<<<4096, 256, 0, stream>>>(xs, ln2g, ln2b, xln);
  run_attn(stream, xs, xln, msb, 1024, QKVraw, Qc, Kc, Vt, P, Am,
           wqkv2, wo2, pwt2, a2qc, a2kc, a2vc, pqk2, qk2o);

  // FFN
  ln_kernel<<<4096, 256, 0, stream>>>(xs, ln3g, ln3b, xln);
  gemm256<EPI_RELU2, false, 256><<<dim3(8, 32, 1), dim3(512), 0, stream>>>(
      xln, xln, 1 << 30, 0, 0, 1024, nullptr, 0,
      wl1, 0, 0, 1024, nullptr, 0, 0, 0,
      1024, 0, H1, 0, 0, 2048, nullptr, 0, 0, 1.f);
  gemm256<EPI_ADDF32, false, 128><<<dim3(8, 32, 1), dim3(512), 0, stream>>>(
      H1, H1, 1 << 30, 0, 0, 2048, nullptr, 0,
      wl2, 0, 0, 2048, nullptr, 0, 0, 0,
      2048, 0, xs, 0, 0, 1024, nullptr, 0, 0, 1.f);

  // final transpose to out[b][1][bins][w]
  tout_kernel<<<dim3(32, 32, 4), dim3(32, 32), 0, stream>>>(xs, outp);
}

// Round 8
// 475.686 us; speedup vs baseline: 1.5074x; 1.0575x over previous
//
#include <hip/hip_runtime.h>
#include <stdint.h>

typedef unsigned short u16;
typedef __bf16 bfv8 __attribute__((ext_vector_type(8)));
typedef float f32x4 __attribute__((ext_vector_type(4)));
typedef unsigned short u16x8 __attribute__((ext_vector_type(8)));

#define DI __device__ __forceinline__

DI u16 f2bf(float f) {
  union { float f; unsigned u; } c; c.f = f;
  unsigned r = c.u + 0x7FFFu + ((c.u >> 16) & 1u);
  return (u16)(r >> 16);
}
DI float bf2f(u16 b) {
  union { unsigned u; float f; } c; c.u = ((unsigned)b) << 16;
  return c.f;
}

enum { EPI_BF16 = 0, EPI_RELU2 = 1, EPI_ADDF32 = 2, EPI_QK = 3 };

#define GLDS(g, l)                                                              \
  __builtin_amdgcn_global_load_lds((const __attribute__((address_space(1))) void*)(g), \
                                   (__attribute__((address_space(3))) void*)(l), 16, 0, 0)

#define VMCNT_BAR(N)                                        \
  do {                                                      \
    asm volatile("s_waitcnt vmcnt(" #N ")" ::: "memory");   \
    __builtin_amdgcn_sched_barrier(0);                      \
    __builtin_amdgcn_s_barrier();                           \
    __builtin_amdgcn_sched_barrier(0);                      \
  } while (0)

#define BAR_ONLY()                                          \
  do {                                                      \
    __builtin_amdgcn_sched_barrier(0);                      \
    __builtin_amdgcn_s_barrier();                           \
    __builtin_amdgcn_sched_barrier(0);                      \
  } while (0)

// C[m,n] = sum_k A[m,k]*B[n,k]. Tile 128x128, BK=64, 512 thr (8 waves 2Mx4N),
// 2-stage double-buffered LDS (64 KB -> 2 blocks/CU; m114 cross-block overlap
// fills barrier drains) with counted vmcnt(4) + setprio.
// Bijective chunked XCD swizzle (m204). LDS XOR swizzle round-1-verified.
// A source selectable per output-column block (n0>=asplit -> Akv).
// KSPLIT: k>=ksp reads A2 (unbatched)/B2 (batched).
template <int EPI, bool KSPLIT>
__global__ __launch_bounds__(512, 4) void gemm128(
    const u16* __restrict__ Aq, const u16* __restrict__ Akv, int asplit,
    long a1q, long a1r, int lda1,
    const u16* __restrict__ A2, int lda2,
    const u16* __restrict__ B1, long b1q, long b1r, int ldb1,
    const u16* __restrict__ B2, long b2q, long b2r, int ldb2,
    int K, int ksp,
    void* __restrict__ Cv, long cq, long cr, int ldc,
    const float* __restrict__ extra, long eq, int lde,
    float scale)
{
  constexpr int NJ = 2;                 // wave: 64m x 32n = 4x2 16x16 frags
  constexpr int SS = 16384;             // u16 per stage: A 128x64 + B 128x64
  __shared__ __align__(16) u16 lds[2 * SS];   // 64 KB
  const int tid = threadIdx.x;
  const int wid = tid >> 6, lane = tid & 63;

  const int gx = gridDim.x, gy = gridDim.y;
  const int nwg = gx * gy * (int)gridDim.z;
  const int flat = blockIdx.x + gx * (blockIdx.y + gy * blockIdx.z);
  const int q = nwg >> 3, r = nwg & 7;
  const int xcd = flat & 7, idx = flat >> 3;
  const int wg = (xcd < r ? xcd * (q + 1) : r * (q + 1) + (xcd - r) * q) + idx;
  const int bx = wg % gx;
  const int tmp = wg / gx;
  const int by = tmp % gy;
  const int bz = tmp / gy;

  const long zq = bz >> 2, zr = bz & 3;
  const int m0 = by * 128, n0 = bx * 128;
  const u16* Ab = ((n0 >= asplit) ? Akv : Aq) + zq * a1q + zr * a1r;
  const u16* Bb = B1 + zq * b1q + zr * b1r;
  const u16* B2b = KSPLIT ? (B2 + zq * b2q + zr * b2r) : (const u16*)nullptr;
  const int wm = (wid >> 2) * 64, wn = (wid & 3) * 32;
  const int fr = lane & 15, fq = lane >> 4;

  f32x4 acc[4][NJ];
#pragma unroll
  for (int i = 0; i < 4; ++i)
#pragma unroll
    for (int j = 0; j < NJ; ++j)
      acc[i][j] = (f32x4){0.f, 0.f, 0.f, 0.f};

  const int nt = K >> 6;

  auto STAGE = [&](int tt, int sb) {
    const int k0 = tt << 6;
    u16* Ld = &lds[sb * SS];
    const u16* Asrc; int la; const u16* Bsrc; int lb;
    if (!KSPLIT || k0 < ksp) { Asrc = Ab + k0; la = lda1; Bsrc = Bb + k0; lb = ldb1; }
    else { Asrc = A2 + (k0 - ksp); la = lda2; Bsrc = B2b + (k0 - ksp); lb = ldb2; }
#pragma unroll
    for (int l = 0; l < 2; ++l) {               // A: 1024 chunks / 512 thr
      int idx2 = (l << 9) + tid;
      int row = idx2 >> 3;
      int sc = ((idx2 & 7) ^ (row & 7)) << 3;   // pre-swizzled global column
      GLDS(Asrc + (size_t)(m0 + row) * la + sc,
           Ld + (((l << 3) + wid) << 9));
    }
#pragma unroll
    for (int l = 0; l < 2; ++l) {               // B: 1024 chunks / 512 thr
      int idx2 = (l << 9) + tid;
      int row = idx2 >> 3;
      int sc = ((idx2 & 7) ^ (row & 7)) << 3;
      GLDS(Bsrc + (size_t)(n0 + row) * lb + sc,
           Ld + 8192 + (((l << 3) + wid) << 9));
    }
  };

  auto COMPUTE = [&](int cb) {
    const u16* As = &lds[cb * SS];
    const u16* Bs = As + 8192;
#pragma unroll
    for (int ks = 0; ks < 2; ++ks) {
      bfv8 av[4];
#pragma unroll
      for (int i = 0; i < 4; ++i) {
        int ra = wm + i * 16 + fr;
        int ca = (((ks << 2) + fq) ^ (ra & 7)) << 3;
        av[i] = *(const bfv8*)&As[(ra << 6) + ca];
      }
      bfv8 bv[2];
#pragma unroll
      for (int j = 0; j < 2; ++j) {
        int rb = wn + (j << 4) + fr;
        int cb2 = (((ks << 2) + fq) ^ (rb & 7)) << 3;
        bv[j] = *(const bfv8*)&Bs[(rb << 6) + cb2];
      }
      __builtin_amdgcn_s_setprio(1);
#pragma unroll
      for (int i = 0; i < 4; ++i) {
        acc[i][0] = __builtin_amdgcn_mfma_f32_16x16x32_bf16(av[i], bv[0], acc[i][0], 0, 0, 0);
        acc[i][1] = __builtin_amdgcn_mfma_f32_16x16x32_bf16(av[i], bv[1], acc[i][1], 0, 0, 0);
      }
      __builtin_amdgcn_s_setprio(0);
    }
  };

  STAGE(0, 0);
  STAGE(1, 1);
  VMCNT_BAR(4);                    // tile 0 landed (tile 1's 4 loads may remain)
  for (int t = 0; t < nt; ++t) {
    COMPUTE(t & 1);
    BAR_ONLY();                    // all waves done reading buf t&1
    if (t + 2 < nt) {
      STAGE(t + 2, t & 1);         // refill freed buffer
      VMCNT_BAR(4);                // tile t+1 ready; t+2's 4 loads stay in flight
    } else if (t + 1 < nt) {
      VMCNT_BAR(0);                // tile t+1 ready (nothing else in flight)
    }
  }

  if constexpr (EPI == EPI_BF16 || EPI == EPI_RELU2) {
    u16* Cb = (u16*)Cv + zq * cq + zr * cr;
#pragma unroll
    for (int i = 0; i < 4; ++i)
#pragma unroll
      for (int j = 0; j < NJ; ++j)
#pragma unroll
        for (int r2 = 0; r2 < 4; ++r2) {
          int row = m0 + wm + i * 16 + (fq << 2) + r2;
          int col = n0 + wn + j * 16 + fr;
          float v = acc[i][j][r2];
          if constexpr (EPI == EPI_RELU2) { v = fmaxf(v, 0.f); v = v * v; }
          Cb[(size_t)row * ldc + col] = f2bf(v);
        }
  } else if constexpr (EPI == EPI_ADDF32) {
    float* Cb = (float*)Cv + zq * cq + zr * cr;
#pragma unroll
    for (int i = 0; i < 4; ++i)
#pragma unroll
      for (int j = 0; j < NJ; ++j)
#pragma unroll
        for (int r2 = 0; r2 < 4; ++r2) {
          int row = m0 + wm + i * 16 + (fq << 2) + r2;
          int col = n0 + wn + j * 16 + fr;
          Cb[(size_t)row * ldc + col] += acc[i][j][r2];
        }
  } else {  // EPI_QK
    float* Cb = (float*)Cv + zq * cq + zr * cr;
    const float* Eb = extra + (size_t)bz * eq;
#pragma unroll
    for (int i = 0; i < 4; ++i)
#pragma unroll
      for (int j = 0; j < NJ; ++j)
#pragma unroll
        for (int r2 = 0; r2 < 4; ++r2) {
          int row = m0 + wm + i * 16 + (fq << 2) + r2;
          int col = n0 + wn + j * 16 + fr;
          Cb[(size_t)row * ldc + col] = acc[i][j][r2] * scale + Eb[(size_t)row * lde + col];
        }
  }
}

// Input projection via global_load_lds DMA staging.
__global__ __launch_bounds__(256) void proj4_kernel(const float* __restrict__ x,
                                                    const float* __restrict__ memp,
                                                    const float* __restrict__ ipw,
                                                    const float* __restrict__ ipb,
                                                    const float* __restrict__ mpw,
                                                    const float* __restrict__ mpb,
                                                    float* __restrict__ xs,
                                                    u16* __restrict__ msb)
{
  __shared__ __align__(16) float sbuf[2][16][256];   // 32 KB
  const int t = threadIdx.x;
  const int wid = t >> 6, lane = t & 63;
  const int task = blockIdx.z >> 2;
  const int b = blockIdx.z & 3;
  const int h0 = blockIdx.x << 4;
  const int w0 = blockIdx.y << 8;
  const float* src = task ? memp : x;
  const float* w8 = task ? mpw : ipw;
  const float bias = task ? mpb[0] : ipb[0];
  const int crot = (blockIdx.x + blockIdx.y + blockIdx.z) & 7;
  float wr[8];
#pragma unroll
  for (int j = 0; j < 8; ++j) wr[j] = w8[(j + crot) & 7];
  float acc[16];
#pragma unroll
  for (int h = 0; h < 16; ++h) acc[h] = bias;
  const size_t bbase = ((size_t)b * 8) << 20;

  auto STAGE_C = [&](int i, int sb) {
    const int c = (i + crot) & 7;
    const float* g = src + bbase + ((size_t)c << 20) + (size_t)h0 * 1024 + w0 + (lane << 2);
#pragma unroll
    for (int l = 0; l < 4; ++l) {
      int row = (wid << 2) + l;
      GLDS(g + (size_t)row * 1024, &sbuf[sb][row][0]);
    }
  };

  STAGE_C(0, 0);
  STAGE_C(1, 1);
#pragma unroll
  for (int i = 0; i < 8; ++i) {
    if (i < 7) VMCNT_BAR(4); else VMCNT_BAR(0);
    {
      const float wc = wr[i];
      const int sb = i & 1;
#pragma unroll
      for (int h = 0; h < 16; ++h)
        acc[h] += sbuf[sb][h][t] * wc;
    }
    BAR_ONLY();
    if (i + 2 < 8) STAGE_C(i + 2, i & 1);
  }

  if (task) {
    u16* d = &msb[((size_t)b * 1024 + w0 + t) * 1024 + h0];
    u16x8 o0, o1;
#pragma unroll
    for (int h = 0; h < 8; ++h) { o0[h] = f2bf(acc[h]); o1[h] = f2bf(acc[h + 8]); }
    *(u16x8*)&d[0] = o0;
    *(u16x8*)&d[8] = o1;
  } else {
    float* d = &xs[((size_t)b * 1024 + w0 + t) * 1024 + h0];
#pragma unroll
    for (int p = 0; p < 4; ++p) {
      f32x4 v = {acc[p * 4], acc[p * 4 + 1], acc[p * 4 + 2], acc[p * 4 + 3]};
      *(f32x4*)&d[p * 4] = v;
    }
  }
}

// LayerNorm over 1024, f32 in -> bf16 out. one block per row.
__global__ __launch_bounds__(256) void ln_kernel(const float* __restrict__ x,
                                                 const float* __restrict__ g,
                                                 const float* __restrict__ b,
                                                 u16* __restrict__ out)
{
  int row = blockIdx.x, tid = threadIdx.x;
  float4 v = ((const float4*)(x + (size_t)row * 1024))[tid];
  float s = v.x + v.y + v.z + v.w;
  float s2 = v.x * v.x + v.y * v.y + v.z * v.z + v.w * v.w;
#pragma unroll
  for (int o = 32; o; o >>= 1) { s += __shfl_down(s, o); s2 += __shfl_down(s2, o); }
  __shared__ float rs[4], rs2[4];
  int wid = tid >> 6, lane = tid & 63;
  if (lane == 0) { rs[wid] = s; rs2[wid] = s2; }
  __syncthreads();
  s = rs[0] + rs[1] + rs[2] + rs[3];
  s2 = rs2[0] + rs2[1] + rs2[2] + rs2[3];
  float mean = s * (1.f / 1024.f);
  float var = s2 * (1.f / 1024.f) - mean * mean;
  float rstd = rsqrtf(var + 1e-5f);
  float4 gv = ((const float4*)g)[tid];
  float4 bv = ((const float4*)b)[tid];
  ushort4 o;
  o.x = f2bf((v.x - mean) * rstd * gv.x + bv.x);
  o.y = f2bf((v.y - mean) * rstd * gv.y + bv.y);
  o.z = f2bf((v.z - mean) * rstd * gv.z + bv.z);
  o.w = f2bf((v.w - mean) * rstd * gv.w + bv.w);
  ((ushort4*)out)[(size_t)row * 256 + tid] = o;
}

// depthwise conv k=3 pad=1 along t for Q (sel=0) and K (sel=1) from fused QKV buffer.
__global__ __launch_bounds__(128) void dwconv_qk_kernel(const u16* __restrict__ qkv,
                                                        const float* __restrict__ qc,
                                                        const float* __restrict__ kc,
                                                        u16* __restrict__ Qc,
                                                        u16* __restrict__ Kc)
{
  int sel = blockIdx.y;
  int row = blockIdx.x;     // b*1024 + t
  int t = row & 1023;
  int c0 = threadIdx.x * 8;
  const u16* r0 = qkv + (size_t)row * 3072 + (sel << 10) + c0;
  const float* wc = sel ? kc : qc;
  u16* dst = (sel ? Kc : Qc) + (size_t)row * 1024 + c0;
  u16x8 zv = {0, 0, 0, 0, 0, 0, 0, 0};
  u16x8 xm = zv, xp = zv;
  if (t > 0) xm = *(const u16x8*)(r0 - 3072);
  u16x8 xc = *(const u16x8*)r0;
  if (t < 1023) xp = *(const u16x8*)(r0 + 3072);
  u16x8 o;
#pragma unroll
  for (int j = 0; j < 8; ++j) {
    int c = c0 + j;
    float v = bf2f(xm[j]) * wc[c * 3 + 0] + bf2f(xc[j]) * wc[c * 3 + 1] + bf2f(xp[j]) * wc[c * 3 + 2];
    o[j] = f2bf(v);
  }
  *(u16x8*)dst = o;
}

// depthwise conv + transposed store for V: out[(b*4+c/256)][c%256][t] from qkv col 2048+c
__global__ __launch_bounds__(1024) void dwconv_t_kernel(const u16* __restrict__ qkv,
                                                        const float* __restrict__ wc,
                                                        u16* __restrict__ out)
{
  __shared__ float tile[32][33];
  int b = blockIdx.z;
  int t = blockIdx.x * 32 + threadIdx.y;
  int c = blockIdx.y * 32 + threadIdx.x;
  size_t base = ((size_t)b * 1024 + t) * 3072 + 2048 + c;
  float xm = (t > 0) ? bf2f(qkv[base - 3072]) : 0.f;
  float xc = bf2f(qkv[base]);
  float xp = (t < 1023) ? bf2f(qkv[base + 3072]) : 0.f;
  tile[threadIdx.y][threadIdx.x] = xm * wc[c * 3 + 0] + xc * wc[c * 3 + 1] + xp * wc[c * 3 + 2];
  __syncthreads();
  int c2 = blockIdx.y * 32 + threadIdx.y;
  int t2 = blockIdx.x * 32 + threadIdx.x;
  int z = b * 4 + (c2 >> 8);
  out[((size_t)z * 256 + (c2 & 255)) * 1024 + t2] = f2bf(tile[threadIdx.x][threadIdx.y]);
}

// row softmax over 1024, f32 in -> bf16 out
__global__ __launch_bounds__(256) void softmax_kernel(const float* __restrict__ qk,
                                                      u16* __restrict__ P)
{
  size_t row = blockIdx.x;
  int tid = threadIdx.x;
  float4 v = ((const float4*)(qk + row * 1024))[tid];
  float m = fmaxf(fmaxf(v.x, v.y), fmaxf(v.z, v.w));
#pragma unroll
  for (int o = 32; o; o >>= 1) m = fmaxf(m, __shfl_down(m, o));
  __shared__ float red[4];
  int wid = tid >> 6, lane = tid & 63;
  if (lane == 0) red[wid] = m;
  __syncthreads();
  m = fmaxf(fmaxf(red[0], red[1]), fmaxf(red[2], red[3]));
  float e0 = __expf(v.x - m), e1 = __expf(v.y - m), e2 = __expf(v.z - m), e3 = __expf(v.w - m);
  float s = e0 + e1 + e2 + e3;
#pragma unroll
  for (int o = 32; o; o >>= 1) s += __shfl_down(s, o);
  __syncthreads();
  if (lane == 0) red[wid] = s;
  __syncthreads();
  s = red[0] + red[1] + red[2] + red[3];
  float rinv = 1.f / s;
  ushort4 o;
  o.x = f2bf(e0 * rinv); o.y = f2bf(e1 * rinv); o.z = f2bf(e2 * rinv); o.w = f2bf(e3 * rinv);
  ((ushort4*)P)[row * 256 + tid] = o;
}

// 12 fused f32->bf16 casts of 1M elements each (weight prep, one launch)
struct CastJobs { const float* s[12]; u16* d[12]; };
__global__ __launch_bounds__(256) void cast12_kernel(CastJobs J)
{
  int j = blockIdx.y;
  int i = blockIdx.x * 256 + threadIdx.x;   // 262144 float4 per job
  float4 v = ((const float4*)J.s[j])[i];
  ushort4 o;
  o.x = f2bf(v.x); o.y = f2bf(v.y); o.z = f2bf(v.z); o.w = f2bf(v.w);
  ((ushort4*)J.d[j])[i] = o;
}

// pw [256][1024] f32 -> pwT [1024][256] bf16
__global__ __launch_bounds__(1024) void pwt_kernel(const float* __restrict__ pw,
                                                   u16* __restrict__ pwT)
{
  __shared__ float tile[32][33];
  int d = blockIdx.y * 32 + threadIdx.y;
  int t = blockIdx.x * 32 + threadIdx.x;
  tile[threadIdx.y][threadIdx.x] = pw[(size_t)d * 1024 + t];
  __syncthreads();
  int t2 = blockIdx.x * 32 + threadIdx.y;
  int d2 = blockIdx.y * 32 + threadIdx.x;
  pwT[(size_t)t2 * 256 + d2] = f2bf(tile[threadIdx.x][threadIdx.y]);
}

// out[b][h][w] = xs[b][w][h], f32
__global__ __launch_bounds__(1024) void tout_kernel(const float* __restrict__ xs,
                                                    float* __restrict__ out)
{
  __shared__ float tile[32][33];
  int b = blockIdx.z;
  int w = blockIdx.x * 32 + threadIdx.y;
  int h = blockIdx.y * 32 + threadIdx.x;
  tile[threadIdx.y][threadIdx.x] = xs[((size_t)b * 1024 + w) * 1024 + h];
  __syncthreads();
  int h2 = blockIdx.y * 32 + threadIdx.y;
  int w2 = blockIdx.x * 32 + threadIdx.x;
  out[((size_t)b * 1024 + h2) * 1024 + w2] = tile[threadIdx.x][threadIdx.y];
}

static void run_attn(hipStream_t stream, float* xs, const u16* qsrc, const u16* kvsrc, int asplit,
                     u16* QKVraw, u16* Qc, u16* Kc, u16* Vt, u16* P, u16* Am,
                     const u16* wqkv, const u16* wo, const u16* pwt,
                     const float* qc, const float* kc, const float* vc,
                     const float* prevqk, float* qko)
{
  dim3 blk(512);
  // fused QKV projection: M=4096, N=3072, K=1024. 768 blocks.
  gemm128<EPI_BF16, false><<<dim3(24, 32, 1), blk, 0, stream>>>(
      qsrc, kvsrc, asplit, 0, 0, 1024, nullptr, 0,
      wqkv, 0, 0, 1024, nullptr, 0, 0, 0,
      1024, 0, QKVraw, 0, 0, 3072, nullptr, 0, 0, 1.f);
  dwconv_qk_kernel<<<dim3(4096, 2), 128, 0, stream>>>(QKVraw, qc, kc, Qc, Kc);
  dwconv_t_kernel<<<dim3(32, 32, 4), dim3(32, 32), 0, stream>>>(QKVraw, vc, Vt);
  // qk = (Q Kt + pwT Qt)/32 + prev, K=512 split at 256. 1024 blocks.
  gemm128<EPI_QK, true><<<dim3(8, 8, 16), blk, 0, stream>>>(
      Qc, Qc, 1 << 30, 1048576, 256, 1024, pwt, 256,
      Kc, 1048576, 256, 1024, Qc, 1048576, 256, 1024,
      512, 256, qko, 4194304, 1048576, 1024, prevqk, 1048576, 1024, 0.03125f);
  softmax_kernel<<<16384, 256, 0, stream>>>(qko, P);
  // PV: per z, [1024x1024]x[1024x256]. 256 blocks.
  gemm128<EPI_BF16, false><<<dim3(2, 8, 16), blk, 0, stream>>>(
      P, P, 1 << 30, 4194304, 1048576, 1024, nullptr, 0,
      Vt, 1048576, 262144, 1024, nullptr, 0, 0, 0,
      1024, 0, Am, 1048576, 256, 1024, nullptr, 0, 0, 1.f);
  // O-proj + residual add into xs (f32). 256 blocks.
  gemm128<EPI_ADDF32, false><<<dim3(8, 32, 1), blk, 0, stream>>>(
      Am, Am, 1 << 30, 0, 0, 1024, nullptr, 0,
      wo, 0, 0, 1024, nullptr, 0, 0, 0,
      1024, 0, xs, 0, 0, 1024, nullptr, 0, 0, 1.f);
}

extern "C" void kernel_launch(void* const* d_in, const int* in_sizes, int n_in,
                              void* d_out, int out_size, void* d_ws, size_t ws_size,
                              hipStream_t stream)
{
  (void)in_sizes; (void)n_in; (void)out_size; (void)ws_size;
  const float* x    = (const float*)d_in[0];
  const float* memp = (const float*)d_in[1];
  const float* pqk1 = (const float*)d_in[2];
  const float* pqk2 = (const float*)d_in[3];
  const float* ip_w = (const float*)d_in[4];
  const float* ip_b = (const float*)d_in[5];
  const float* mp_w = (const float*)d_in[6];
  const float* mp_b = (const float*)d_in[7];
  const float* ln1g = (const float*)d_in[8];
  const float* ln1b = (const float*)d_in[9];
  const float* ln2g = (const float*)d_in[10];
  const float* ln2b = (const float*)d_in[11];
  const float* ln3g = (const float*)d_in[12];
  const float* ln3b = (const float*)d_in[13];
  const float* a1qw = (const float*)d_in[14];
  const float* a1qc = (const float*)d_in[15];
  const float* a1kw = (const float*)d_in[16];
  const float* a1kc = (const float*)d_in[17];
  const float* a1vw = (const float*)d_in[18];
  const float* a1vc = (const float*)d_in[19];
  const float* a1ow = (const float*)d_in[20];
  const float* a1pw = (const float*)d_in[21];
  const float* a2qw = (const float*)d_in[22];
  const float* a2qc = (const float*)d_in[23];
  const float* a2kw = (const float*)d_in[24];
  const float* a2kc = (const float*)d_in[25];
  const float* a2vw = (const float*)d_in[26];
  const float* a2vc = (const float*)d_in[27];
  const float* a2ow = (const float*)d_in[28];
  const float* a2pw = (const float*)d_in[29];
  const float* l1w  = (const float*)d_in[30];
  const float* l2w  = (const float*)d_in[31];

  float* outp = (float*)d_out;
  float* qk1o = outp + 4194304;    // [4][4][1024][1024]
  float* qk2o = outp + 20971520;

  const size_t MB = 1024 * 1024;
  char* W = (char*)d_ws;
  float* xs   = (float*)(W);             // 16MB f32 [4][1024w][1024h]
  u16* msb    = (u16*)(W + 16 * MB);     // 8MB bf16
  u16* xln    = (u16*)(W + 24 * MB);     // 8MB
  u16* QKVraw = (u16*)(W + 32 * MB);     // 24MB [4096][3072]
  u16* Qc     = (u16*)(W + 56 * MB);     // 8MB
  u16* Kc     = (u16*)(W + 64 * MB);     // 8MB
  u16* Vt     = (u16*)(W + 72 * MB);     // 8MB  [16][256][1024]
  u16* P      = (u16*)(W + 80 * MB);     // 32MB [16][1024][1024]
  u16* Am     = (u16*)(W + 112 * MB);    // 8MB
  u16* wqkv1  = (u16*)(W + 120 * MB);    // 6MB [3072][1024]
  u16* wqkv2  = (u16*)(W + 126 * MB);    // 6MB
  u16* wo1    = (u16*)(W + 132 * MB);    // 2MB
  u16* wo2    = (u16*)(W + 134 * MB);    // 2MB
  u16* wl1    = (u16*)(W + 136 * MB);    // 4MB [2048][1024]
  u16* wl2    = (u16*)(W + 140 * MB);    // 4MB [1024][2048]
  u16* pwt1   = (u16*)(W + 144 * MB);    // 0.5MB [1024][256]
  u16* pwt2   = (u16*)(W + 144 * MB + 512 * 1024);
  u16* H1     = QKVraw;                  // 16MB overlay (dead in FFN)

  CastJobs J;
  J.s[0] = a1qw; J.d[0] = wqkv1;
  J.s[1] = a1kw; J.d[1] = wqkv1 + 1048576;
  J.s[2] = a1vw; J.d[2] = wqkv1 + 2097152;
  J.s[3] = a2qw; J.d[3] = wqkv2;
  J.s[4] = a2kw; J.d[4] = wqkv2 + 1048576;
  J.s[5] = a2vw; J.d[5] = wqkv2 + 2097152;
  J.s[6] = a1ow; J.d[6] = wo1;
  J.s[7] = a2ow; J.d[7] = wo2;
  J.s[8] = l1w;            J.d[8] = wl1;
  J.s[9] = l1w + 1048576;  J.d[9] = wl1 + 1048576;
  J.s[10] = l2w;           J.d[10] = wl2;
  J.s[11] = l2w + 1048576; J.d[11] = wl2 + 1048576;
  cast12_kernel<<<dim3(1024, 12), 256, 0, stream>>>(J);
  pwt_kernel<<<dim3(32, 8, 1), dim3(32, 32), 0, stream>>>(a1pw, pwt1);
  pwt_kernel<<<dim3(32, 8, 1), dim3(32, 32), 0, stream>>>(a2pw, pwt2);

  // input projections: DMA-staged (global_load_lds) read path
  proj4_kernel<<<dim3(64, 4, 8), 256, 0, stream>>>(
      x, memp, ip_w, ip_b, mp_w, mp_b, xs, msb);

  // attention 1 (self): q and kv both from LN1(xs)
  ln_kernel<<<4096, 256, 0, stream>>>(xs, ln1g, ln1b, xln);
  run_attn(stream, xs, xln, xln, 1 << 30, QKVraw, Qc, Kc, Vt, P, Am,
           wqkv1, wo1, pwt1, a1qc, a1kc, a1vc, pqk1, qk1o);

  // attention 2 (cross): q from LN2(xs), kv from ms
  ln_kernel<<<4096, 256, 0, stream>>>(xs, ln2g, ln2b, xln);
  run_attn(stream, xs, xln, msb, 1024, QKVraw, Qc, Kc, Vt, P, Am,
           wqkv2, wo2, pwt2, a2qc, a2kc, a2vc, pqk2, qk2o);

  // FFN
  ln_kernel<<<4096, 256, 0, stream>>>(xs, ln3g, ln3b, xln);
  gemm128<EPI_RELU2, false><<<dim3(16, 32, 1), dim3(512), 0, stream>>>(
      xln, xln, 1 << 30, 0, 0, 1024, nullptr, 0,
      wl1, 0, 0, 1024, nullptr, 0, 0, 0,
      1024, 0, H1, 0, 0, 2048, nullptr, 0, 0, 1.f);
  gemm128<EPI_ADDF32, false><<<dim3(8, 32, 1), dim3(512), 0, stream>>>(
      H1, H1, 1 << 30, 0, 0, 2048, nullptr, 0,
      wl2, 0, 0, 2048, nullptr, 0, 0, 0,
      2048, 0, xs, 0, 0, 1024, nullptr, 0, 0, 1.f);

  // final transpose to out[b][1][bins][w]
  tout_kernel<<<dim3(32, 32, 4), dim3(32, 32), 0, stream>>>(xs, outp);
}